// Round 12
// baseline (376.372 us; speedup 1.0000x reference)
//
#include <hip/hip_runtime.h>

typedef __bf16 bf16;
typedef __attribute__((ext_vector_type(8))) __bf16 bf16x8;
typedef __attribute__((ext_vector_type(4))) __bf16 bf16x4;
typedef __attribute__((ext_vector_type(2))) __bf16 bf16x2;
typedef __attribute__((ext_vector_type(4))) float f32x4;
typedef __attribute__((ext_vector_type(2))) float f32x2;

static constexpr int NPIX = 4096;                    // 64*64
static constexpr float BN_SC = 0.9999950000374997f;  // 1/sqrt(1+1e-5)
static constexpr float ATT_EPS = 1e-15f;

__device__ __forceinline__ float hswish_f(float v) {
  return v * fminf(fmaxf(v + 3.0f, 0.0f), 6.0f) * (1.0f / 6.0f);
}

__device__ __forceinline__ void gload16(const void* g, void* l) {
  __builtin_amdgcn_global_load_lds(
      (const __attribute__((address_space(1))) unsigned int*)g,
      (__attribute__((address_space(3))) unsigned int*)l, 16, 0, 0);
}

__device__ __forceinline__ float b2f_lo(unsigned int u) {
  union { unsigned int i; float f; } v; v.i = u << 16; return v.f;
}
__device__ __forceinline__ float b2f_hi(unsigned int u) {
  union { unsigned int i; float f; } v; v.i = u & 0xffff0000u; return v.f;
}
__device__ __forceinline__ unsigned short f2b_u(float f) {
  union { float f; unsigned int i; } v; v.f = f;
  unsigned int r = v.i + 0x7FFFu + ((v.i >> 16) & 1u);
  return (unsigned short)(r >> 16);
}
// relu on 2 packed bf16 in a u32
__device__ __forceinline__ unsigned int relu2(unsigned int v) {
  const unsigned int s = v & 0x80008000u;
  const unsigned int m = (s >> 15) * 0xFFFFu;
  return v & ~m;
}

// ---------------- x (f32 NCHW) -> x_nhwc (bf16) ----------------
__global__ __launch_bounds__(256)
void x_to_nhwc(const float* __restrict__ x, bf16* __restrict__ xn) {
  __shared__ float t[32][65];
  const int img = blockIdx.z;
  const int n0 = blockIdx.x * 64, c0 = blockIdx.y * 32;
  const int tid = threadIdx.x;
  const float* xb = x + ((size_t)img * 256 + c0) * NPIX + n0;
  {
    const int col = tid & 63, r0 = tid >> 6;
#pragma unroll
    for (int i = 0; i < 8; ++i) {
      const int r = r0 + i * 4;
      t[r][col] = xb[(size_t)r * NPIX + col];
    }
  }
  __syncthreads();
  const int n = tid & 63, cq = tid >> 6;
  bf16x8 v;
#pragma unroll
  for (int j = 0; j < 8; ++j) v[j] = (bf16)t[cq * 8 + j][n];
  *(bf16x8*)(xn + ((size_t)img * NPIX + n0 + n) * 256 + c0 + cq * 8) = v;
}

// ---------------- merged f32 -> bf16 weight convert (proj | e | p) ----------------
__global__ void wcvt3(const float* __restrict__ W_proj, const float* __restrict__ W_e,
                      const float* __restrict__ W_p, bf16* __restrict__ o_proj,
                      bf16* __restrict__ o_e, bf16* __restrict__ o_p) {
  const int i = blockIdx.x * 256 + threadIdx.x;
  if (i < 131072) o_proj[i] = (bf16)W_proj[i];
  else if (i < 393216) o_e[i - 131072] = (bf16)W_e[i - 131072];
  else o_p[i - 393216] = (bf16)W_p[i - 393216];
}

// ---------------- W_qkv permuted convert ----------------
__global__ void wqkv_perm(const float* __restrict__ w, bf16* __restrict__ o) {
  const int row = blockIdx.x;  // 0..767 (new index)
  const int t = row >> 8, r = row & 255, h = r >> 5, d = r & 31;
  const int oldrow = h * 96 + t * 32 + d;
  o[row * 256 + threadIdx.x] = (bf16)w[oldrow * 256 + threadIdx.x];
}

// ---------------- MFMA GEMM ----------------
template<int EPI>
__global__ __launch_bounds__(256, 3)
void mfma_gemm(const bf16* __restrict__ A, const bf16* __restrict__ Bact,
               bf16* __restrict__ Yb, float* __restrict__ Yf,
               const int M, const int K,
               const float* __restrict__ p0, const float* __restrict__ p1,
               const bf16* __restrict__ res)
{
  __shared__ __attribute__((aligned(16))) char ldsA[16384];
  __shared__ __attribute__((aligned(16))) char ldsB[16384];
  const int img = blockIdx.z;
  const int n0 = blockIdx.x * 128;
  const int m0 = blockIdx.y * 128;
  const bf16* Bi = Bact + (size_t)img * NPIX * K;
  const int tid = threadIdx.x;
  const int w = tid >> 6, l = tid & 63;
  const int g = l >> 4, ln = l & 15;
  const int wr = w >> 1, wc = w & 1;
  const int lrow = l >> 3;
  const int sofs = (((l & 7) ^ lrow) << 4);

  f32x4 acc[4][4];
#pragma unroll
  for (int i = 0; i < 4; ++i)
#pragma unroll
    for (int j = 0; j < 4; ++j) acc[i][j] = (f32x4){0.f, 0.f, 0.f, 0.f};

  const char* Abase = (const char*)(A + (size_t)m0 * K);
  const char* Bbase = (const char*)(Bi + (size_t)n0 * K);
  const size_t rowb = (size_t)K * 2;
  const int swz = (ln & 7) << 4;

  const int nk = K >> 6;
  for (int kt = 0; kt < nk; ++kt) {
    const int k0b = kt << 7;
#pragma unroll
    for (int i = 0; i < 4; ++i) {
      const int q = (w << 2) + i;
      const int r = q * 8 + lrow;
      gload16(Abase + (size_t)r * rowb + k0b + sofs, ldsA + q * 1024);
    }
#pragma unroll
    for (int i = 0; i < 4; ++i) {
      const int q = (w << 2) + i;
      const int r = q * 8 + lrow;
      gload16(Bbase + (size_t)r * rowb + k0b + sofs, ldsB + q * 1024);
    }
    __syncthreads();
#pragma unroll
    for (int kk = 0; kk < 2; ++kk) {
      bf16x8 av[4], bv[4];
#pragma unroll
      for (int f = 0; f < 4; ++f) {
        const int ra = wr * 64 + f * 16 + ln;
        const int rb = wc * 64 + f * 16 + ln;
        const int kb = kk * 64 + (g << 4);
        av[f] = *(const bf16x8*)(ldsA + ra * 128 + (kb ^ swz));
        bv[f] = *(const bf16x8*)(ldsB + rb * 128 + (kb ^ swz));
      }
#pragma unroll
      for (int fi = 0; fi < 4; ++fi)
#pragma unroll
        for (int fj = 0; fj < 4; ++fj)
          acc[fi][fj] = __builtin_amdgcn_mfma_f32_16x16x32_bf16(
              av[fi], bv[fj], acc[fi][fj], 0, 0, 0);
    }
    __syncthreads();
  }

#pragma unroll
  for (int fi = 0; fi < 4; ++fi) {
    const int m4 = m0 + wr * 64 + fi * 16 + g * 4;
    f32x4 P0 = {0.f, 0.f, 0.f, 0.f}, P1 = {0.f, 0.f, 0.f, 0.f};
    if (EPI == 1 || EPI == 3) { P0 = *(const f32x4*)(p0 + m4); P1 = *(const f32x4*)(p1 + m4); }
    if (EPI == 2) { P0 = *(const f32x4*)(p0 + m4); }
#pragma unroll
    for (int fj = 0; fj < 4; ++fj) {
      const int n = n0 + wc * 64 + fj * 16 + ln;
      if (EPI == 3) {
        const bf16x4 yr = *(const bf16x4*)(res + ((size_t)img * NPIX + n) * 256 + m4);
        float* op = Yf + ((size_t)img * 256 + m4) * NPIX + n;
#pragma unroll
        for (int r = 0; r < 4; ++r)
          op[(size_t)r * NPIX] = P0[r] * BN_SC * acc[fi][fj][r] + P1[r] + (float)yr[r];
      } else {
        bf16x4 sv;
        if (EPI == 0) {
#pragma unroll
          for (int r = 0; r < 4; ++r) sv[r] = (bf16)acc[fi][fj][r];
        } else if (EPI == 1) {
          const bf16x4 xr = *(const bf16x4*)(res + ((size_t)img * NPIX + n) * 256 + m4);
#pragma unroll
          for (int r = 0; r < 4; ++r)
            sv[r] = (bf16)(P0[r] * BN_SC * acc[fi][fj][r] + P1[r] + (float)xr[r]);
        } else {
#pragma unroll
          for (int r = 0; r < 4; ++r)
            sv[r] = (bf16)hswish_f(acc[fi][fj][r] + P0[r]);
        }
        *(bf16x4*)(Yb + ((size_t)img * NPIX + n) * M + m4) = sv;
      }
    }
  }
}

// ---------------- fused dw5x5 + per-group 32x32 pointwise (NHWC), v4.1 ----------------
// 512 thr, tile = 256 px (4 image rows), halo 8x68.  Staging issued first.
__global__ __launch_bounds__(512)
void dw5pw_nhwc(const bf16* __restrict__ qkv, const float* __restrict__ W5,
                const float* __restrict__ Wpw, bf16* __restrict__ ag) {
  const int gch = blockIdx.y, img = blockIdx.z;
  const int t_ = gch >> 3, hh_ = gch & 7;
  const int n0 = blockIdx.x * 256;
  const int r0 = n0 >> 6;                        // first of 4 image rows
  __shared__ __attribute__((aligned(16))) unsigned int sInT[16 * 548];  // 35072 B
  __shared__ __attribute__((aligned(16))) unsigned int sS32[256 * 20];  // 20480 B
  __shared__ __attribute__((aligned(16))) bf16 sPw[32 * 32];            // 2048 B
  const int tid = threadIdx.x;
  // halo staging first (longest-latency loads issue earliest)
  for (int i = tid; i < 2176; i += 512) {
    const int s = i & 3, hp = i >> 2;
    const int hr = hp / 68, hc = hp - hr * 68;
    const int gr = r0 + hr - 2, gc = hc - 2;
    uint4 vv = {0u, 0u, 0u, 0u};
    if (gr >= 0 && gr < 64 && gc >= 0 && gc < 64)
      vv = *(const uint4*)(qkv + ((size_t)img * NPIX + gr * 64 + gc) * 768 + gch * 32 + s * 8);
    unsigned int* rp = sInT + (s * 4) * 548 + hp;
    rp[0] = vv.x; rp[548] = vv.y; rp[1096] = vv.z; rp[1644] = vv.w;
  }
  for (int i = tid; i < 1024; i += 512) sPw[i] = (bf16)Wpw[(hh_ * 3 + t_) * 1024 + i];
  // per-thread dw weights for channels {2ci, 2ci+1}
  const int ci = tid & 15;
  f32x2 w2[25];
  {
    const float* wp0 = W5 + (size_t)(hh_ * 96 + t_ * 32 + 2 * ci) * 25;
#pragma unroll
    for (int q = 0; q < 25; ++q) w2[q] = (f32x2){wp0[q], wp0[25 + q]};
  }
  __syncthreads();
  {  // phase 1: depthwise 5x5, packed f32 pairs; pg 0..31, 8 px each
    const int pg = tid >> 4;
    const int p0 = pg * 8;
    const int prow = p0 >> 6, pcol = p0 & 63;
    f32x2 a2[8];
#pragma unroll
    for (int px = 0; px < 8; ++px) a2[px] = (f32x2){0.f, 0.f};
#pragma unroll
    for (int ky = 0; ky < 5; ++ky) {
      const unsigned int* wp = &sInT[ci * 548 + (prow + ky) * 68 + pcol];
      const uint4 qa = *(const uint4*)wp;
      const uint4 qb = *(const uint4*)(wp + 4);
      const uint4 qc = *(const uint4*)(wp + 8);
      const unsigned int win[12] = {qa.x, qa.y, qa.z, qa.w, qb.x, qb.y, qb.z, qb.w,
                                    qc.x, qc.y, qc.z, qc.w};
      f32x2 val[12];
#pragma unroll
      for (int j = 0; j < 12; ++j) val[j] = (f32x2){b2f_lo(win[j]), b2f_hi(win[j])};
#pragma unroll
      for (int px = 0; px < 8; ++px)
#pragma unroll
        for (int kx = 0; kx < 5; ++kx)
          a2[px] = val[px + kx] * w2[ky * 5 + kx] + a2[px];   // v_pk_fma_f32
    }
#pragma unroll
    for (int px = 0; px < 8; ++px) {
      const unsigned int pk = (unsigned int)f2b_u(a2[px][0]) | ((unsigned int)f2b_u(a2[px][1]) << 16);
      sS32[(p0 + px) * 20 + ci] = pk;
    }
  }
  __syncthreads();
  {  // phase 2: pw 32x32 via MFMA; wave w handles p-tiles {2w, 2w+1}
    const int w = tid >> 6, l = tid & 63;
    const int lg = l >> 4, ln = l & 15;
    f32x4 acc[2][2];
#pragma unroll
    for (int i = 0; i < 2; ++i)
#pragma unroll
      for (int j = 0; j < 2; ++j) acc[i][j] = (f32x4){0.f, 0.f, 0.f, 0.f};
    bf16x8 av[2], bv[2];
#pragma unroll
    for (int et = 0; et < 2; ++et)
      av[et] = *(const bf16x8*)((const char*)sPw + (et * 16 + ln) * 64 + lg * 16);
#pragma unroll
    for (int pt = 0; pt < 2; ++pt)
      bv[pt] = *(const bf16x8*)((const char*)sS32 + ((2 * w + pt) * 16 + ln) * 80 + lg * 16);
#pragma unroll
    for (int et = 0; et < 2; ++et)
#pragma unroll
      for (int pt = 0; pt < 2; ++pt)
        acc[et][pt] = __builtin_amdgcn_mfma_f32_16x16x32_bf16(av[et], bv[pt], acc[et][pt], 0, 0, 0);
#pragma unroll
    for (int et = 0; et < 2; ++et)
#pragma unroll
      for (int pt = 0; pt < 2; ++pt) {
        const int e0 = et * 16 + lg * 4;
        const int p = n0 + (2 * w + pt) * 16 + ln;
        bf16x4 sv;
#pragma unroll
        for (int r = 0; r < 4; ++r) sv[r] = (bf16)acc[et][pt][r];
        *(bf16x4*)(ag + ((size_t)img * NPIX + p) * 768 + gch * 32 + e0) = sv;
      }
  }
}

// ---------------- vk partial v3: T14 async-stage (issue-early, write-late) ----------
__global__ __launch_bounds__(256)
void vk_part(const bf16* __restrict__ qkv, const bf16* __restrict__ ag,
             float* __restrict__ partial) {
  const int chunk = blockIdx.x, src = blockIdx.y, img = blockIdx.z;
  const bf16* base = (src == 0 ? qkv : ag) + (size_t)img * NPIX * 768 + 256;
  __shared__ __attribute__((aligned(16))) char tile[32 * 1024];
  const int tid = threadIdx.x;
  const int h = tid >> 5;
  const int r5 = tid & 31;
  const int et = r5 & 3;
  const int dq = r5 >> 2;
  const int spx = tid >> 3, sseg = tid & 7;
  const char* gp0 = (const char*)(base + (size_t)(chunk * 64 + spx) * 768) + sseg * 128;
  f32x2 acc[4][4];
#pragma unroll
  for (int i = 0; i < 4; ++i)
#pragma unroll
    for (int j = 0; j < 4; ++j) acc[i][j] = (f32x2){0.f, 0.f};
  f32x2 dsum[4] = {(f32x2){0.f,0.f},(f32x2){0.f,0.f},(f32x2){0.f,0.f},(f32x2){0.f,0.f}};
  uint4 rv[8];
  // preload sub 0
#pragma unroll
  for (int i = 0; i < 8; ++i) {
    uint4 v = *(const uint4*)(gp0 + i * 16);
    if (sseg < 4) { v.x = relu2(v.x); v.y = relu2(v.y); v.z = relu2(v.z); v.w = relu2(v.w); }
    rv[i] = v;
  }
#pragma unroll
  for (int sub = 0; sub < 2; ++sub) {
    if (sub) __syncthreads();   // prior consume done before overwrite
    {
      char* lp = tile + spx * 1024;
      const int swz = (spx & 7) << 4;
#pragma unroll
      for (int i = 0; i < 8; ++i)
        *(uint4*)(lp + ((sseg * 128 + i * 16) ^ swz)) = rv[i];
    }
    __syncthreads();
    if (sub == 0) {  // issue next-sub loads; latency hides under consume below
      const char* gp1 = gp0 + (size_t)32 * 768 * 2;
#pragma unroll
      for (int i = 0; i < 8; ++i) {
        uint4 v = *(const uint4*)(gp1 + i * 16);
        if (sseg < 4) { v.x = relu2(v.x); v.y = relu2(v.y); v.z = relu2(v.z); v.w = relu2(v.w); }
        rv[i] = v;
      }
    }
    for (int nn = 0; nn < 32; ++nn) {
      const char* row = tile + nn * 1024;
      const int swzn = (nn & 7) << 4;
      f32x2 kp[4];
#pragma unroll
      for (int j = 0; j < 4; ++j) {
        const unsigned int kk = *(const unsigned int*)(row + ((h * 64 + (et * 4 + j) * 4) ^ swzn));
        kp[j] = (f32x2){b2f_lo(kk), b2f_hi(kk)};
      }
      const unsigned int v0 = *(const unsigned int*)(row + ((512 + h * 64 + dq * 8) ^ swzn));
      const unsigned int v1 = *(const unsigned int*)(row + ((512 + h * 64 + dq * 8 + 4) ^ swzn));
      const float vd[4] = {b2f_lo(v0), b2f_hi(v0), b2f_lo(v1), b2f_hi(v1)};
#pragma unroll
      for (int i = 0; i < 4; ++i)
#pragma unroll
        for (int j = 0; j < 4; ++j)
          acc[i][j] = (f32x2){vd[i], vd[i]} * kp[j] + acc[i][j];
      if (dq == 0) {
#pragma unroll
        for (int j = 0; j < 4; ++j) dsum[j] = dsum[j] + kp[j];
      }
    }
  }
  float* pb = partial + ((size_t)((img * 2 + src) * 64 + chunk)) * 8448;
#pragma unroll
  for (int i = 0; i < 4; ++i) {
    const int d = dq * 4 + i;
#pragma unroll
    for (int j = 0; j < 4; ++j) {
      pb[h * 1056 + d * 32 + et * 8 + j * 2]     = acc[i][j][0];
      pb[h * 1056 + d * 32 + et * 8 + j * 2 + 1] = acc[i][j][1];
    }
  }
  if (dq == 0) {
#pragma unroll
    for (int j = 0; j < 4; ++j) {
      pb[h * 1056 + 1024 + et * 8 + j * 2]     = dsum[j][0];
      pb[h * 1056 + 1024 + et * 8 + j * 2 + 1] = dsum[j][1];
    }
  }
}

// ---------------- vk reduce ----------------
__global__ __launch_bounds__(256)
void vk_reduce(const float* __restrict__ partial, bf16* __restrict__ svkT,
               float* __restrict__ dvec) {
  const int h = blockIdx.x & 15, img = blockIdx.x >> 4;
  const int tid = threadIdx.x;
  const int e = tid & 31, dq = tid >> 5;
  const int src = h >> 3, hh = h & 7;
  const float* pb = partial + (size_t)((img * 2 + src) * 64) * 8448 + hh * 1056;
  float a[4] = {};
  for (int c = 0; c < 64; ++c) {
    const float* pc = pb + (size_t)c * 8448;
#pragma unroll
    for (int j = 0; j < 4; ++j) a[j] += pc[(dq * 4 + j) * 32 + e];
  }
  bf16x4 o;
#pragma unroll
  for (int j = 0; j < 4; ++j) o[j] = (bf16)a[j];
  *(bf16x4*)(svkT + (((size_t)img * 16 + h) * 32 + e) * 32 + dq * 4) = o;
  if (dq == 0) {
    float ds = 0.f;
    for (int c = 0; c < 64; ++c) ds += pb[(size_t)c * 8448 + 1024 + e];
    dvec[((size_t)img * 16 + h) * 32 + e] = ds;
  }
}

// ---------------- attention apply v3: packed-f32 inner math ----------------
__global__ __launch_bounds__(256)
void att_pix(const bf16* __restrict__ qkv, const bf16* __restrict__ ag,
             const bf16* __restrict__ svkT, const float* __restrict__ dvec,
             bf16* __restrict__ att) {
  const int pc = blockIdx.x;      // 16 px each
  const int img = blockIdx.z;
  __shared__ __attribute__((aligned(16))) unsigned int squ[16][264];
  __shared__ __attribute__((aligned(16))) bf16 ssvk[16 * 1024];
  __shared__ __attribute__((aligned(8))) float sdv[512];
  const int tid = threadIdx.x;
  const int px0 = pc * 16;
  const int px = tid >> 4, s = tid & 15;
  {
    const bf16* srcp = (s < 8 ? qkv : ag) + (size_t)(img * NPIX + px0 + px) * 768 + (s & 7) * 32;
#pragma unroll
    for (int i = 0; i < 4; ++i) {
      uint4 v = *(const uint4*)((const char*)srcp + i * 16);
      v.x = relu2(v.x); v.y = relu2(v.y); v.z = relu2(v.z); v.w = relu2(v.w);
      *(uint4*)&squ[px][s * 16 + i * 4] = v;
    }
  }
  {
    const bf16* sb = svkT + (size_t)img * 16384;
    for (int i = tid; i < 2048; i += 256)
      *(bf16x8*)(ssvk + i * 8) = *(const bf16x8*)(sb + i * 8);
    const float* db = dvec + (size_t)img * 512;
    for (int i = tid; i < 512; i += 256) sdv[i] = db[i];
  }
  __syncthreads();
  const int sd = s, d0 = sd * 2;
  const unsigned int* sv32 = (const unsigned int*)ssvk;
  bf16* ob = att + (size_t)(img * NPIX + px0 + px) * 512;
#pragma unroll
  for (int h = 0; h < 16; ++h) {
    const unsigned int* qp = &squ[px][h * 16];
    const unsigned int* kp = sv32 + h * 512 + sd;
    const f32x2* dp = (const f32x2*)&sdv[h * 32];
    f32x2 accp = (f32x2){0.f, 0.f};     // (a0, a1)
    f32x2 denp = (f32x2){0.f, 0.f};     // pairwise den
#pragma unroll
    for (int e2 = 0; e2 < 16; ++e2) {
      const unsigned int qq = qp[e2];
      const float q0 = b2f_lo(qq), q1 = b2f_hi(qq);
      const unsigned int w0 = kp[(2 * e2) * 16];
      const unsigned int w1 = kp[(2 * e2 + 1) * 16];
      const f32x2 w0p = (f32x2){b2f_lo(w0), b2f_hi(w0)};
      const f32x2 w1p = (f32x2){b2f_lo(w1), b2f_hi(w1)};
      accp = (f32x2){q0, q0} * w0p + accp;     // v_pk_fma_f32
      accp = (f32x2){q1, q1} * w1p + accp;
      denp = (f32x2){q0, q1} * dp[e2] + denp;
    }
    const float inv = 1.f / (denp[0] + denp[1] + ATT_EPS);
    bf16x2 o; o[0] = (bf16)(accp[0] * inv); o[1] = (bf16)(accp[1] * inv);
    *(bf16x2*)(ob + h * 32 + d0) = o;
  }
}

// ---------------- depthwise 3x3 + bias + hswish (NHWC), v2.1: 32-row walk ----
#define DW3_LOADROW(r, sl)                                                     \
  {                                                                            \
    for (int cs = 0; cs < 3; ++cs) {                                           \
      const int cc = col + cs - 1;                                             \
      if ((unsigned)(r) < 64u && (unsigned)cc < 64u) {                         \
        const uint2 v = *(const uint2*)(ib + (size_t)((r) * 64 + cc) * 1024);  \
        rr[sl][cs][0] = (f32x2){b2f_lo(v.x), b2f_hi(v.x)};                     \
        rr[sl][cs][1] = (f32x2){b2f_lo(v.y), b2f_hi(v.y)};                     \
      } else {                                                                 \
        rr[sl][cs][0] = (f32x2){0.f, 0.f};                                     \
        rr[sl][cs][1] = (f32x2){0.f, 0.f};                                     \
      }                                                                        \
    }                                                                          \
  }

__global__ __launch_bounds__(256)
void dw3_nhwc(const bf16* __restrict__ ein, const float* __restrict__ w3,
              const float* __restrict__ bias, bf16* __restrict__ dout) {
  const int img = blockIdx.z;
  const int r0 = blockIdx.y * 32;
  const int col = blockIdx.x;
  const int tid = threadIdx.x;
  const int ch = tid * 4;
  f32x2 wv[9][2];
#pragma unroll
  for (int p = 0; p < 2; ++p)
#pragma unroll
    for (int q = 0; q < 9; ++q)
      wv[q][p] = (f32x2){w3[(ch + 2 * p) * 9 + q], w3[(ch + 2 * p + 1) * 9 + q]};
  f32x2 bv[2];
  bv[0] = (f32x2){bias[ch], bias[ch + 1]};
  bv[1] = (f32x2){bias[ch + 2], bias[ch + 3]};
  const bf16* ib = ein + (size_t)img * NPIX * 1024 + ch;
  bf16* ob = dout + (size_t)img * NPIX * 1024 + ch;
  f32x2 rr[3][3][2];
  DW3_LOADROW(r0 - 1, 0);
  DW3_LOADROW(r0, 1);
#pragma unroll
  for (int i = 0; i < 32; ++i) {
    const int slm = i % 3, sl0 = (i + 1) % 3, slp = (i + 2) % 3;
    DW3_LOADROW(r0 + i + 1, slp);
    f32x2 a[2] = {bv[0], bv[1]};
#pragma unroll
    for (int kx = 0; kx < 3; ++kx)
#pragma unroll
      for (int p = 0; p < 2; ++p) {
        a[p] = rr[slm][kx][p] * wv[0 * 3 + kx][p] + a[p];
        a[p] = rr[sl0][kx][p] * wv[1 * 3 + kx][p] + a[p];
        a[p] = rr[slp][kx][p] * wv[2 * 3 + kx][p] + a[p];
      }
    uint2 o;
    o.x = (unsigned)f2b_u(hswish_f(a[0][0])) | ((unsigned)f2b_u(hswish_f(a[0][1])) << 16);
    o.y = (unsigned)f2b_u(hswish_f(a[1][0])) | ((unsigned)f2b_u(hswish_f(a[1][1])) << 16);
    *(uint2*)(ob + (size_t)((r0 + i) * 64 + col) * 1024) = o;
  }
}

// ---------------- launch ----------------
extern "C" void kernel_launch(void* const* d_in, const int* in_sizes, int n_in,
                              void* d_out, int out_size, void* d_ws, size_t ws_size,
                              hipStream_t stream) {
  const float* x      = (const float*)d_in[0];
  const float* W_qkv  = (const float*)d_in[1];
  const float* W_dw5  = (const float*)d_in[2];
  const float* W_pw   = (const float*)d_in[3];
  const float* W_proj = (const float*)d_in[4];
  const float* g_proj = (const float*)d_in[5];
  const float* b_proj = (const float*)d_in[6];
  const float* W_e    = (const float*)d_in[7];
  const float* b_e    = (const float*)d_in[8];
  const float* W_dw3  = (const float*)d_in[9];
  const float* b_dw3  = (const float*)d_in[10];
  const float* W_p    = (const float*)d_in[11];
  const float* g_p    = (const float*)d_in[12];
  const float* b_p    = (const float*)d_in[13];
  float* out = (float*)d_out;

  int nb = 8;
  while (nb > 1) {
    size_t need = (size_t)nb * 25331712ull + 1703936ull + 1024;
    if (need <= ws_size) break;
    nb >>= 1;
  }

  char* p = (char*)d_ws;
  float* partial = (float*)p;                 p += (size_t)nb * 4325376;
  float* dvec    = (float*)p;                 p += (size_t)nb * 2048;
  bf16* wq_bf    = (bf16*)p;                  p += 196608ull * 2;
  bf16* wproj_bf = (bf16*)p;                  p += 131072ull * 2;
  bf16* we_bf    = (bf16*)p;                  p += 262144ull * 2;
  bf16* wp_bf    = (bf16*)p;                  p += 262144ull * 2;
  bf16* svkT     = (bf16*)p;                  p += (size_t)nb * 32768;
  bf16* arena    = (bf16*)p;
  bf16* xn   = arena;
  bf16* qkvb = arena + (size_t)nb * 1048576;
  bf16* agb  = qkvb + (size_t)nb * 3145728;
  bf16* attb = agb + (size_t)nb * 3145728;
  bf16* yb   = attb + (size_t)nb * 2097152;
  bf16* eb   = qkvb;
  bf16* db   = qkvb + (size_t)nb * 4194304;

  wqkv_perm<<<768, 256, 0, stream>>>(W_qkv, wq_bf);
  wcvt3<<<2560, 256, 0, stream>>>(W_proj, W_e, W_p, wproj_bf, we_bf, wp_bf);

  for (int b0 = 0; b0 < 8; b0 += nb) {
    const float* x_c = x + (size_t)b0 * 256 * NPIX;
    float* out_c = out + (size_t)b0 * 256 * NPIX;

    x_to_nhwc<<<dim3(64, 8, nb), 256, 0, stream>>>(x_c, xn);
    mfma_gemm<0><<<dim3(32, 6, nb), 256, 0, stream>>>(wq_bf, xn, qkvb, nullptr,
                                                      768, 256, nullptr, nullptr, nullptr);
    dw5pw_nhwc<<<dim3(16, 24, nb), 512, 0, stream>>>(qkvb, W_dw5, W_pw, agb);
    vk_part<<<dim3(64, 2, nb), 256, 0, stream>>>(qkvb, agb, partial);
    vk_reduce<<<nb * 16, 256, 0, stream>>>(partial, svkT, dvec);
    att_pix<<<dim3(256, 1, nb), 256, 0, stream>>>(qkvb, agb, svkT, dvec, attb);
    mfma_gemm<1><<<dim3(32, 2, nb), 256, 0, stream>>>(wproj_bf, attb, yb, nullptr,
                                                      256, 512, g_proj, b_proj, xn);
    mfma_gemm<2><<<dim3(32, 8, nb), 256, 0, stream>>>(we_bf, yb, eb, nullptr,
                                                      1024, 256, b_e, nullptr, nullptr);
    dw3_nhwc<<<dim3(64, 2, nb), 256, 0, stream>>>(eb, W_dw3, b_dw3, db);
    mfma_gemm<3><<<dim3(32, 2, nb), 256, 0, stream>>>(wp_bf, db, nullptr, out_c,
                                                      256, 1024, g_p, b_p, yb);
  }
}

// Round 13
// 365.319 us; speedup vs baseline: 1.0303x; 1.0303x over previous
//
#include <hip/hip_runtime.h>

typedef __bf16 bf16;
typedef __attribute__((ext_vector_type(8))) __bf16 bf16x8;
typedef __attribute__((ext_vector_type(4))) __bf16 bf16x4;
typedef __attribute__((ext_vector_type(2))) __bf16 bf16x2;
typedef __attribute__((ext_vector_type(4))) float f32x4;
typedef __attribute__((ext_vector_type(2))) float f32x2;

static constexpr int NPIX = 4096;                    // 64*64
static constexpr float BN_SC = 0.9999950000374997f;  // 1/sqrt(1+1e-5)
static constexpr float ATT_EPS = 1e-15f;

__device__ __forceinline__ float hswish_f(float v) {
  return v * fminf(fmaxf(v + 3.0f, 0.0f), 6.0f) * (1.0f / 6.0f);
}

__device__ __forceinline__ void gload16(const void* g, void* l) {
  __builtin_amdgcn_global_load_lds(
      (const __attribute__((address_space(1))) unsigned int*)g,
      (__attribute__((address_space(3))) unsigned int*)l, 16, 0, 0);
}

__device__ __forceinline__ float b2f_lo(unsigned int u) {
  union { unsigned int i; float f; } v; v.i = u << 16; return v.f;
}
__device__ __forceinline__ float b2f_hi(unsigned int u) {
  union { unsigned int i; float f; } v; v.i = u & 0xffff0000u; return v.f;
}
__device__ __forceinline__ unsigned short f2b_u(float f) {
  union { float f; unsigned int i; } v; v.f = f;
  unsigned int r = v.i + 0x7FFFu + ((v.i >> 16) & 1u);
  return (unsigned short)(r >> 16);
}
// relu on 2 packed bf16 in a u32
__device__ __forceinline__ unsigned int relu2(unsigned int v) {
  const unsigned int s = v & 0x80008000u;
  const unsigned int m = (s >> 15) * 0xFFFFu;
  return v & ~m;
}

// ---------------- x (f32 NCHW) -> x_nhwc (bf16) ----------------
__global__ __launch_bounds__(256)
void x_to_nhwc(const float* __restrict__ x, bf16* __restrict__ xn) {
  __shared__ float t[32][65];
  const int img = blockIdx.z;
  const int n0 = blockIdx.x * 64, c0 = blockIdx.y * 32;
  const int tid = threadIdx.x;
  const float* xb = x + ((size_t)img * 256 + c0) * NPIX + n0;
  {
    const int col = tid & 63, r0 = tid >> 6;
#pragma unroll
    for (int i = 0; i < 8; ++i) {
      const int r = r0 + i * 4;
      t[r][col] = xb[(size_t)r * NPIX + col];
    }
  }
  __syncthreads();
  const int n = tid & 63, cq = tid >> 6;
  bf16x8 v;
#pragma unroll
  for (int j = 0; j < 8; ++j) v[j] = (bf16)t[cq * 8 + j][n];
  *(bf16x8*)(xn + ((size_t)img * NPIX + n0 + n) * 256 + c0 + cq * 8) = v;
}

// ---------------- merged f32 -> bf16 weight convert (proj | e | p) ----------------
__global__ void wcvt3(const float* __restrict__ W_proj, const float* __restrict__ W_e,
                      const float* __restrict__ W_p, bf16* __restrict__ o_proj,
                      bf16* __restrict__ o_e, bf16* __restrict__ o_p) {
  const int i = blockIdx.x * 256 + threadIdx.x;
  if (i < 131072) o_proj[i] = (bf16)W_proj[i];
  else if (i < 393216) o_e[i - 131072] = (bf16)W_e[i - 131072];
  else o_p[i - 393216] = (bf16)W_p[i - 393216];
}

// ---------------- W_qkv permuted convert ----------------
__global__ void wqkv_perm(const float* __restrict__ w, bf16* __restrict__ o) {
  const int row = blockIdx.x;  // 0..767 (new index)
  const int t = row >> 8, r = row & 255, h = r >> 5, d = r & 31;
  const int oldrow = h * 96 + t * 32 + d;
  o[row * 256 + threadIdx.x] = (bf16)w[oldrow * 256 + threadIdx.x];
}

// ---------------- MFMA GEMM ----------------
template<int EPI>
__global__ __launch_bounds__(256, 3)
void mfma_gemm(const bf16* __restrict__ A, const bf16* __restrict__ Bact,
               bf16* __restrict__ Yb, float* __restrict__ Yf,
               const int M, const int K,
               const float* __restrict__ p0, const float* __restrict__ p1,
               const bf16* __restrict__ res)
{
  __shared__ __attribute__((aligned(16))) char ldsA[16384];
  __shared__ __attribute__((aligned(16))) char ldsB[16384];
  const int img = blockIdx.z;
  const int n0 = blockIdx.x * 128;
  const int m0 = blockIdx.y * 128;
  const bf16* Bi = Bact + (size_t)img * NPIX * K;
  const int tid = threadIdx.x;
  const int w = tid >> 6, l = tid & 63;
  const int g = l >> 4, ln = l & 15;
  const int wr = w >> 1, wc = w & 1;
  const int lrow = l >> 3;
  const int sofs = (((l & 7) ^ lrow) << 4);

  f32x4 acc[4][4];
#pragma unroll
  for (int i = 0; i < 4; ++i)
#pragma unroll
    for (int j = 0; j < 4; ++j) acc[i][j] = (f32x4){0.f, 0.f, 0.f, 0.f};

  const char* Abase = (const char*)(A + (size_t)m0 * K);
  const char* Bbase = (const char*)(Bi + (size_t)n0 * K);
  const size_t rowb = (size_t)K * 2;
  const int swz = (ln & 7) << 4;

  const int nk = K >> 6;
  for (int kt = 0; kt < nk; ++kt) {
    const int k0b = kt << 7;
#pragma unroll
    for (int i = 0; i < 4; ++i) {
      const int q = (w << 2) + i;
      const int r = q * 8 + lrow;
      gload16(Abase + (size_t)r * rowb + k0b + sofs, ldsA + q * 1024);
    }
#pragma unroll
    for (int i = 0; i < 4; ++i) {
      const int q = (w << 2) + i;
      const int r = q * 8 + lrow;
      gload16(Bbase + (size_t)r * rowb + k0b + sofs, ldsB + q * 1024);
    }
    __syncthreads();
#pragma unroll
    for (int kk = 0; kk < 2; ++kk) {
      bf16x8 av[4], bv[4];
#pragma unroll
      for (int f = 0; f < 4; ++f) {
        const int ra = wr * 64 + f * 16 + ln;
        const int rb = wc * 64 + f * 16 + ln;
        const int kb = kk * 64 + (g << 4);
        av[f] = *(const bf16x8*)(ldsA + ra * 128 + (kb ^ swz));
        bv[f] = *(const bf16x8*)(ldsB + rb * 128 + (kb ^ swz));
      }
#pragma unroll
      for (int fi = 0; fi < 4; ++fi)
#pragma unroll
        for (int fj = 0; fj < 4; ++fj)
          acc[fi][fj] = __builtin_amdgcn_mfma_f32_16x16x32_bf16(
              av[fi], bv[fj], acc[fi][fj], 0, 0, 0);
    }
    __syncthreads();
  }

#pragma unroll
  for (int fi = 0; fi < 4; ++fi) {
    const int m4 = m0 + wr * 64 + fi * 16 + g * 4;
    f32x4 P0 = {0.f, 0.f, 0.f, 0.f}, P1 = {0.f, 0.f, 0.f, 0.f};
    if (EPI == 1 || EPI == 3) { P0 = *(const f32x4*)(p0 + m4); P1 = *(const f32x4*)(p1 + m4); }
    if (EPI == 2) { P0 = *(const f32x4*)(p0 + m4); }
#pragma unroll
    for (int fj = 0; fj < 4; ++fj) {
      const int n = n0 + wc * 64 + fj * 16 + ln;
      if (EPI == 3) {
        const bf16x4 yr = *(const bf16x4*)(res + ((size_t)img * NPIX + n) * 256 + m4);
        float* op = Yf + ((size_t)img * 256 + m4) * NPIX + n;
#pragma unroll
        for (int r = 0; r < 4; ++r)
          op[(size_t)r * NPIX] = P0[r] * BN_SC * acc[fi][fj][r] + P1[r] + (float)yr[r];
      } else {
        bf16x4 sv;
        if (EPI == 0) {
#pragma unroll
          for (int r = 0; r < 4; ++r) sv[r] = (bf16)acc[fi][fj][r];
        } else if (EPI == 1) {
          const bf16x4 xr = *(const bf16x4*)(res + ((size_t)img * NPIX + n) * 256 + m4);
#pragma unroll
          for (int r = 0; r < 4; ++r)
            sv[r] = (bf16)(P0[r] * BN_SC * acc[fi][fj][r] + P1[r] + (float)xr[r]);
        } else {
#pragma unroll
          for (int r = 0; r < 4; ++r)
            sv[r] = (bf16)hswish_f(acc[fi][fj][r] + P0[r]);
        }
        *(bf16x4*)(Yb + ((size_t)img * NPIX + n) * M + m4) = sv;
      }
    }
  }
}

// ---------------- fused dw5x5 + per-group 32x32 pointwise (NHWC), v4.1 ----------------
// 512 thr, tile = 256 px (4 image rows), halo 8x68.  Staging issued first.
__global__ __launch_bounds__(512)
void dw5pw_nhwc(const bf16* __restrict__ qkv, const float* __restrict__ W5,
                const float* __restrict__ Wpw, bf16* __restrict__ ag) {
  const int gch = blockIdx.y, img = blockIdx.z;
  const int t_ = gch >> 3, hh_ = gch & 7;
  const int n0 = blockIdx.x * 256;
  const int r0 = n0 >> 6;                        // first of 4 image rows
  __shared__ __attribute__((aligned(16))) unsigned int sInT[16 * 548];  // 35072 B
  __shared__ __attribute__((aligned(16))) unsigned int sS32[256 * 20];  // 20480 B
  __shared__ __attribute__((aligned(16))) bf16 sPw[32 * 32];            // 2048 B
  const int tid = threadIdx.x;
  // halo staging first (longest-latency loads issue earliest)
  for (int i = tid; i < 2176; i += 512) {
    const int s = i & 3, hp = i >> 2;
    const int hr = hp / 68, hc = hp - hr * 68;
    const int gr = r0 + hr - 2, gc = hc - 2;
    uint4 vv = {0u, 0u, 0u, 0u};
    if (gr >= 0 && gr < 64 && gc >= 0 && gc < 64)
      vv = *(const uint4*)(qkv + ((size_t)img * NPIX + gr * 64 + gc) * 768 + gch * 32 + s * 8);
    unsigned int* rp = sInT + (s * 4) * 548 + hp;
    rp[0] = vv.x; rp[548] = vv.y; rp[1096] = vv.z; rp[1644] = vv.w;
  }
  for (int i = tid; i < 1024; i += 512) sPw[i] = (bf16)Wpw[(hh_ * 3 + t_) * 1024 + i];
  // per-thread dw weights for channels {2ci, 2ci+1}
  const int ci = tid & 15;
  f32x2 w2[25];
  {
    const float* wp0 = W5 + (size_t)(hh_ * 96 + t_ * 32 + 2 * ci) * 25;
#pragma unroll
    for (int q = 0; q < 25; ++q) w2[q] = (f32x2){wp0[q], wp0[25 + q]};
  }
  __syncthreads();
  {  // phase 1: depthwise 5x5, packed f32 pairs; pg 0..31, 8 px each
    const int pg = tid >> 4;
    const int p0 = pg * 8;
    const int prow = p0 >> 6, pcol = p0 & 63;
    f32x2 a2[8];
#pragma unroll
    for (int px = 0; px < 8; ++px) a2[px] = (f32x2){0.f, 0.f};
#pragma unroll
    for (int ky = 0; ky < 5; ++ky) {
      const unsigned int* wp = &sInT[ci * 548 + (prow + ky) * 68 + pcol];
      const uint4 qa = *(const uint4*)wp;
      const uint4 qb = *(const uint4*)(wp + 4);
      const uint4 qc = *(const uint4*)(wp + 8);
      const unsigned int win[12] = {qa.x, qa.y, qa.z, qa.w, qb.x, qb.y, qb.z, qb.w,
                                    qc.x, qc.y, qc.z, qc.w};
      f32x2 val[12];
#pragma unroll
      for (int j = 0; j < 12; ++j) val[j] = (f32x2){b2f_lo(win[j]), b2f_hi(win[j])};
#pragma unroll
      for (int px = 0; px < 8; ++px)
#pragma unroll
        for (int kx = 0; kx < 5; ++kx)
          a2[px] = val[px + kx] * w2[ky * 5 + kx] + a2[px];   // v_pk_fma_f32
    }
#pragma unroll
    for (int px = 0; px < 8; ++px) {
      const unsigned int pk = (unsigned int)f2b_u(a2[px][0]) | ((unsigned int)f2b_u(a2[px][1]) << 16);
      sS32[(p0 + px) * 20 + ci] = pk;
    }
  }
  __syncthreads();
  {  // phase 2: pw 32x32 via MFMA; wave w handles p-tiles {2w, 2w+1}
    const int w = tid >> 6, l = tid & 63;
    const int lg = l >> 4, ln = l & 15;
    f32x4 acc[2][2];
#pragma unroll
    for (int i = 0; i < 2; ++i)
#pragma unroll
      for (int j = 0; j < 2; ++j) acc[i][j] = (f32x4){0.f, 0.f, 0.f, 0.f};
    bf16x8 av[2], bv[2];
#pragma unroll
    for (int et = 0; et < 2; ++et)
      av[et] = *(const bf16x8*)((const char*)sPw + (et * 16 + ln) * 64 + lg * 16);
#pragma unroll
    for (int pt = 0; pt < 2; ++pt)
      bv[pt] = *(const bf16x8*)((const char*)sS32 + ((2 * w + pt) * 16 + ln) * 80 + lg * 16);
#pragma unroll
    for (int et = 0; et < 2; ++et)
#pragma unroll
      for (int pt = 0; pt < 2; ++pt)
        acc[et][pt] = __builtin_amdgcn_mfma_f32_16x16x32_bf16(av[et], bv[pt], acc[et][pt], 0, 0, 0);
#pragma unroll
    for (int et = 0; et < 2; ++et)
#pragma unroll
      for (int pt = 0; pt < 2; ++pt) {
        const int e0 = et * 16 + lg * 4;
        const int p = n0 + (2 * w + pt) * 16 + ln;
        bf16x4 sv;
#pragma unroll
        for (int r = 0; r < 4; ++r) sv[r] = (bf16)acc[et][pt][r];
        *(bf16x4*)(ag + ((size_t)img * NPIX + p) * 768 + gch * 32 + e0) = sv;
      }
  }
}

// ---------------- vk partial v2 (reverted from v3 spill regression) ----------------
__global__ __launch_bounds__(256)
void vk_part(const bf16* __restrict__ qkv, const bf16* __restrict__ ag,
             float* __restrict__ partial) {
  const int chunk = blockIdx.x, src = blockIdx.y, img = blockIdx.z;
  const bf16* base = (src == 0 ? qkv : ag) + (size_t)img * NPIX * 768 + 256;
  __shared__ __attribute__((aligned(16))) char tile[32 * 1024];
  const int tid = threadIdx.x;
  const int h = tid >> 5;
  const int r5 = tid & 31;
  const int et = r5 & 3;
  const int dq = r5 >> 2;
  const int spx = tid >> 3, sseg = tid & 7;
  f32x2 acc[4][4];
#pragma unroll
  for (int i = 0; i < 4; ++i)
#pragma unroll
    for (int j = 0; j < 4; ++j) acc[i][j] = (f32x2){0.f, 0.f};
  f32x2 dsum[4] = {(f32x2){0.f,0.f},(f32x2){0.f,0.f},(f32x2){0.f,0.f},(f32x2){0.f,0.f}};
  for (int sub = 0; sub < 2; ++sub) {
    __syncthreads();
    {
      const int px0 = chunk * 64 + sub * 32;
      const char* gp = (const char*)(base + (size_t)(px0 + spx) * 768) + sseg * 128;
      char* lp = tile + spx * 1024;
      const int swz = (spx & 7) << 4;
#pragma unroll
      for (int i = 0; i < 8; ++i) {
        uint4 v = *(const uint4*)(gp + i * 16);
        if (sseg < 4) {
          v.x = relu2(v.x); v.y = relu2(v.y); v.z = relu2(v.z); v.w = relu2(v.w);
        }
        *(uint4*)(lp + ((sseg * 128 + i * 16) ^ swz)) = v;
      }
    }
    __syncthreads();
    for (int nn = 0; nn < 32; ++nn) {
      const char* row = tile + nn * 1024;
      const int swzn = (nn & 7) << 4;
      f32x2 kp[4];
#pragma unroll
      for (int j = 0; j < 4; ++j) {
        const unsigned int kk = *(const unsigned int*)(row + ((h * 64 + (et * 4 + j) * 4) ^ swzn));
        kp[j] = (f32x2){b2f_lo(kk), b2f_hi(kk)};
      }
      const unsigned int v0 = *(const unsigned int*)(row + ((512 + h * 64 + dq * 8) ^ swzn));
      const unsigned int v1 = *(const unsigned int*)(row + ((512 + h * 64 + dq * 8 + 4) ^ swzn));
      const float vd[4] = {b2f_lo(v0), b2f_hi(v0), b2f_lo(v1), b2f_hi(v1)};
#pragma unroll
      for (int i = 0; i < 4; ++i)
#pragma unroll
        for (int j = 0; j < 4; ++j)
          acc[i][j] = (f32x2){vd[i], vd[i]} * kp[j] + acc[i][j];
      if (dq == 0) {
#pragma unroll
        for (int j = 0; j < 4; ++j) dsum[j] = dsum[j] + kp[j];
      }
    }
  }
  float* pb = partial + ((size_t)((img * 2 + src) * 64 + chunk)) * 8448;
#pragma unroll
  for (int i = 0; i < 4; ++i) {
    const int d = dq * 4 + i;
#pragma unroll
    for (int j = 0; j < 4; ++j) {
      pb[h * 1056 + d * 32 + et * 8 + j * 2]     = acc[i][j][0];
      pb[h * 1056 + d * 32 + et * 8 + j * 2 + 1] = acc[i][j][1];
    }
  }
  if (dq == 0) {
#pragma unroll
    for (int j = 0; j < 4; ++j) {
      pb[h * 1056 + 1024 + et * 8 + j * 2]     = dsum[j][0];
      pb[h * 1056 + 1024 + et * 8 + j * 2 + 1] = dsum[j][1];
    }
  }
}

// ---------------- vk reduce ----------------
__global__ __launch_bounds__(256)
void vk_reduce(const float* __restrict__ partial, bf16* __restrict__ svkT,
               float* __restrict__ dvec) {
  const int h = blockIdx.x & 15, img = blockIdx.x >> 4;
  const int tid = threadIdx.x;
  const int e = tid & 31, dq = tid >> 5;
  const int src = h >> 3, hh = h & 7;
  const float* pb = partial + (size_t)((img * 2 + src) * 64) * 8448 + hh * 1056;
  float a[4] = {};
  for (int c = 0; c < 64; ++c) {
    const float* pc = pb + (size_t)c * 8448;
#pragma unroll
    for (int j = 0; j < 4; ++j) a[j] += pc[(dq * 4 + j) * 32 + e];
  }
  bf16x4 o;
#pragma unroll
  for (int j = 0; j < 4; ++j) o[j] = (bf16)a[j];
  *(bf16x4*)(svkT + (((size_t)img * 16 + h) * 32 + e) * 32 + dq * 4) = o;
  if (dq == 0) {
    float ds = 0.f;
    for (int c = 0; c < 64; ++c) ds += pb[(size_t)c * 8448 + 1024 + e];
    dvec[((size_t)img * 16 + h) * 32 + e] = ds;
  }
}

// ---------------- attention apply v3: packed-f32 inner math ----------------
__global__ __launch_bounds__(256)
void att_pix(const bf16* __restrict__ qkv, const bf16* __restrict__ ag,
             const bf16* __restrict__ svkT, const float* __restrict__ dvec,
             bf16* __restrict__ att) {
  const int pc = blockIdx.x;      // 16 px each
  const int img = blockIdx.z;
  __shared__ __attribute__((aligned(16))) unsigned int squ[16][264];
  __shared__ __attribute__((aligned(16))) bf16 ssvk[16 * 1024];
  __shared__ __attribute__((aligned(8))) float sdv[512];
  const int tid = threadIdx.x;
  const int px0 = pc * 16;
  const int px = tid >> 4, s = tid & 15;
  {
    const bf16* srcp = (s < 8 ? qkv : ag) + (size_t)(img * NPIX + px0 + px) * 768 + (s & 7) * 32;
#pragma unroll
    for (int i = 0; i < 4; ++i) {
      uint4 v = *(const uint4*)((const char*)srcp + i * 16);
      v.x = relu2(v.x); v.y = relu2(v.y); v.z = relu2(v.z); v.w = relu2(v.w);
      *(uint4*)&squ[px][s * 16 + i * 4] = v;
    }
  }
  {
    const bf16* sb = svkT + (size_t)img * 16384;
    for (int i = tid; i < 2048; i += 256)
      *(bf16x8*)(ssvk + i * 8) = *(const bf16x8*)(sb + i * 8);
    const float* db = dvec + (size_t)img * 512;
    for (int i = tid; i < 512; i += 256) sdv[i] = db[i];
  }
  __syncthreads();
  const int sd = s, d0 = sd * 2;
  const unsigned int* sv32 = (const unsigned int*)ssvk;
  bf16* ob = att + (size_t)(img * NPIX + px0 + px) * 512;
#pragma unroll
  for (int h = 0; h < 16; ++h) {
    const unsigned int* qp = &squ[px][h * 16];
    const unsigned int* kp = sv32 + h * 512 + sd;
    const f32x2* dp = (const f32x2*)&sdv[h * 32];
    f32x2 accp = (f32x2){0.f, 0.f};     // (a0, a1)
    f32x2 denp = (f32x2){0.f, 0.f};     // pairwise den
#pragma unroll
    for (int e2 = 0; e2 < 16; ++e2) {
      const unsigned int qq = qp[e2];
      const float q0 = b2f_lo(qq), q1 = b2f_hi(qq);
      const unsigned int w0 = kp[(2 * e2) * 16];
      const unsigned int w1 = kp[(2 * e2 + 1) * 16];
      const f32x2 w0p = (f32x2){b2f_lo(w0), b2f_hi(w0)};
      const f32x2 w1p = (f32x2){b2f_lo(w1), b2f_hi(w1)};
      accp = (f32x2){q0, q0} * w0p + accp;     // v_pk_fma_f32
      accp = (f32x2){q1, q1} * w1p + accp;
      denp = (f32x2){q0, q1} * dp[e2] + denp;
    }
    const float inv = 1.f / (denp[0] + denp[1] + ATT_EPS);
    bf16x2 o; o[0] = (bf16)(accp[0] * inv); o[1] = (bf16)(accp[1] * inv);
    *(bf16x2*)(ob + h * 32 + d0) = o;
  }
}

// ---------------- depthwise 3x3 + bias + hswish (NHWC), v2.1: 32-row walk ----
#define DW3_LOADROW(r, sl)                                                     \
  {                                                                            \
    for (int cs = 0; cs < 3; ++cs) {                                           \
      const int cc = col + cs - 1;                                             \
      if ((unsigned)(r) < 64u && (unsigned)cc < 64u) {                         \
        const uint2 v = *(const uint2*)(ib + (size_t)((r) * 64 + cc) * 1024);  \
        rr[sl][cs][0] = (f32x2){b2f_lo(v.x), b2f_hi(v.x)};                     \
        rr[sl][cs][1] = (f32x2){b2f_lo(v.y), b2f_hi(v.y)};                     \
      } else {                                                                 \
        rr[sl][cs][0] = (f32x2){0.f, 0.f};                                     \
        rr[sl][cs][1] = (f32x2){0.f, 0.f};                                     \
      }                                                                        \
    }                                                                          \
  }

__global__ __launch_bounds__(256)
void dw3_nhwc(const bf16* __restrict__ ein, const float* __restrict__ w3,
              const float* __restrict__ bias, bf16* __restrict__ dout) {
  const int img = blockIdx.z;
  const int r0 = blockIdx.y * 32;
  const int col = blockIdx.x;
  const int tid = threadIdx.x;
  const int ch = tid * 4;
  f32x2 wv[9][2];
#pragma unroll
  for (int p = 0; p < 2; ++p)
#pragma unroll
    for (int q = 0; q < 9; ++q)
      wv[q][p] = (f32x2){w3[(ch + 2 * p) * 9 + q], w3[(ch + 2 * p + 1) * 9 + q]};
  f32x2 bv[2];
  bv[0] = (f32x2){bias[ch], bias[ch + 1]};
  bv[1] = (f32x2){bias[ch + 2], bias[ch + 3]};
  const bf16* ib = ein + (size_t)img * NPIX * 1024 + ch;
  bf16* ob = dout + (size_t)img * NPIX * 1024 + ch;
  f32x2 rr[3][3][2];
  DW3_LOADROW(r0 - 1, 0);
  DW3_LOADROW(r0, 1);
#pragma unroll
  for (int i = 0; i < 32; ++i) {
    const int slm = i % 3, sl0 = (i + 1) % 3, slp = (i + 2) % 3;
    DW3_LOADROW(r0 + i + 1, slp);
    f32x2 a[2] = {bv[0], bv[1]};
#pragma unroll
    for (int kx = 0; kx < 3; ++kx)
#pragma unroll
      for (int p = 0; p < 2; ++p) {
        a[p] = rr[slm][kx][p] * wv[0 * 3 + kx][p] + a[p];
        a[p] = rr[sl0][kx][p] * wv[1 * 3 + kx][p] + a[p];
        a[p] = rr[slp][kx][p] * wv[2 * 3 + kx][p] + a[p];
      }
    uint2 o;
    o.x = (unsigned)f2b_u(hswish_f(a[0][0])) | ((unsigned)f2b_u(hswish_f(a[0][1])) << 16);
    o.y = (unsigned)f2b_u(hswish_f(a[1][0])) | ((unsigned)f2b_u(hswish_f(a[1][1])) << 16);
    *(uint2*)(ob + (size_t)((r0 + i) * 64 + col) * 1024) = o;
  }
}

// ---------------- launch ----------------
extern "C" void kernel_launch(void* const* d_in, const int* in_sizes, int n_in,
                              void* d_out, int out_size, void* d_ws, size_t ws_size,
                              hipStream_t stream) {
  const float* x      = (const float*)d_in[0];
  const float* W_qkv  = (const float*)d_in[1];
  const float* W_dw5  = (const float*)d_in[2];
  const float* W_pw   = (const float*)d_in[3];
  const float* W_proj = (const float*)d_in[4];
  const float* g_proj = (const float*)d_in[5];
  const float* b_proj = (const float*)d_in[6];
  const float* W_e    = (const float*)d_in[7];
  const float* b_e    = (const float*)d_in[8];
  const float* W_dw3  = (const float*)d_in[9];
  const float* b_dw3  = (const float*)d_in[10];
  const float* W_p    = (const float*)d_in[11];
  const float* g_p    = (const float*)d_in[12];
  const float* b_p    = (const float*)d_in[13];
  float* out = (float*)d_out;

  int nb = 8;
  while (nb > 1) {
    size_t need = (size_t)nb * 25331712ull + 1703936ull + 1024;
    if (need <= ws_size) break;
    nb >>= 1;
  }

  char* p = (char*)d_ws;
  float* partial = (float*)p;                 p += (size_t)nb * 4325376;
  float* dvec    = (float*)p;                 p += (size_t)nb * 2048;
  bf16* wq_bf    = (bf16*)p;                  p += 196608ull * 2;
  bf16* wproj_bf = (bf16*)p;                  p += 131072ull * 2;
  bf16* we_bf    = (bf16*)p;                  p += 262144ull * 2;
  bf16* wp_bf    = (bf16*)p;                  p += 262144ull * 2;
  bf16* svkT     = (bf16*)p;                  p += (size_t)nb * 32768;
  bf16* arena    = (bf16*)p;
  bf16* xn   = arena;
  bf16* qkvb = arena + (size_t)nb * 1048576;
  bf16* agb  = qkvb + (size_t)nb * 3145728;
  bf16* attb = agb + (size_t)nb * 3145728;
  bf16* yb   = attb + (size_t)nb * 2097152;
  bf16* eb   = qkvb;
  bf16* db   = qkvb + (size_t)nb * 4194304;

  wqkv_perm<<<768, 256, 0, stream>>>(W_qkv, wq_bf);
  wcvt3<<<2560, 256, 0, stream>>>(W_proj, W_e, W_p, wproj_bf, we_bf, wp_bf);

  for (int b0 = 0; b0 < 8; b0 += nb) {
    const float* x_c = x + (size_t)b0 * 256 * NPIX;
    float* out_c = out + (size_t)b0 * 256 * NPIX;

    x_to_nhwc<<<dim3(64, 8, nb), 256, 0, stream>>>(x_c, xn);
    mfma_gemm<0><<<dim3(32, 6, nb), 256, 0, stream>>>(wq_bf, xn, qkvb, nullptr,
                                                      768, 256, nullptr, nullptr, nullptr);
    dw5pw_nhwc<<<dim3(16, 24, nb), 512, 0, stream>>>(qkvb, W_dw5, W_pw, agb);
    vk_part<<<dim3(64, 2, nb), 256, 0, stream>>>(qkvb, agb, partial);
    vk_reduce<<<nb * 16, 256, 0, stream>>>(partial, svkT, dvec);
    att_pix<<<dim3(256, 1, nb), 256, 0, stream>>>(qkvb, agb, svkT, dvec, attb);
    mfma_gemm<1><<<dim3(32, 2, nb), 256, 0, stream>>>(wproj_bf, attb, yb, nullptr,
                                                      256, 512, g_proj, b_proj, xn);
    mfma_gemm<2><<<dim3(32, 8, nb), 256, 0, stream>>>(we_bf, yb, eb, nullptr,
                                                      1024, 256, b_e, nullptr, nullptr);
    dw3_nhwc<<<dim3(64, 2, nb), 256, 0, stream>>>(eb, W_dw3, b_dw3, db);
    mfma_gemm<3><<<dim3(32, 2, nb), 256, 0, stream>>>(wp_bf, db, nullptr, out_c,
                                                      256, 1024, g_p, b_p, yb);
  }
}

// Round 14
// 362.855 us; speedup vs baseline: 1.0373x; 1.0068x over previous
//
#include <hip/hip_runtime.h>

typedef __bf16 bf16;
typedef __attribute__((ext_vector_type(8))) __bf16 bf16x8;
typedef __attribute__((ext_vector_type(4))) __bf16 bf16x4;
typedef __attribute__((ext_vector_type(2))) __bf16 bf16x2;
typedef __attribute__((ext_vector_type(4))) float f32x4;
typedef __attribute__((ext_vector_type(2))) float f32x2;

static constexpr int NPIX = 4096;                    // 64*64
static constexpr float BN_SC = 0.9999950000374997f;  // 1/sqrt(1+1e-5)
static constexpr float ATT_EPS = 1e-15f;

__device__ __forceinline__ float hswish_f(float v) {
  return v * fminf(fmaxf(v + 3.0f, 0.0f), 6.0f) * (1.0f / 6.0f);
}

__device__ __forceinline__ void gload16(const void* g, void* l) {
  __builtin_amdgcn_global_load_lds(
      (const __attribute__((address_space(1))) unsigned int*)g,
      (__attribute__((address_space(3))) unsigned int*)l, 16, 0, 0);
}

__device__ __forceinline__ float b2f_lo(unsigned int u) {
  union { unsigned int i; float f; } v; v.i = u << 16; return v.f;
}
__device__ __forceinline__ float b2f_hi(unsigned int u) {
  union { unsigned int i; float f; } v; v.i = u & 0xffff0000u; return v.f;
}
__device__ __forceinline__ unsigned short f2b_u(float f) {
  union { float f; unsigned int i; } v; v.f = f;
  unsigned int r = v.i + 0x7FFFu + ((v.i >> 16) & 1u);
  return (unsigned short)(r >> 16);
}
// relu on 2 packed bf16 in a u32
__device__ __forceinline__ unsigned int relu2(unsigned int v) {
  const unsigned int s = v & 0x80008000u;
  const unsigned int m = (s >> 15) * 0xFFFFu;
  return v & ~m;
}

// ---------------- x (f32 NCHW) -> x_nhwc (bf16) ----------------
__global__ __launch_bounds__(256)
void x_to_nhwc(const float* __restrict__ x, bf16* __restrict__ xn) {
  __shared__ float t[32][65];
  const int img = blockIdx.z;
  const int n0 = blockIdx.x * 64, c0 = blockIdx.y * 32;
  const int tid = threadIdx.x;
  const float* xb = x + ((size_t)img * 256 + c0) * NPIX + n0;
  {
    const int col = tid & 63, r0 = tid >> 6;
#pragma unroll
    for (int i = 0; i < 8; ++i) {
      const int r = r0 + i * 4;
      t[r][col] = xb[(size_t)r * NPIX + col];
    }
  }
  __syncthreads();
  const int n = tid & 63, cq = tid >> 6;
  bf16x8 v;
#pragma unroll
  for (int j = 0; j < 8; ++j) v[j] = (bf16)t[cq * 8 + j][n];
  *(bf16x8*)(xn + ((size_t)img * NPIX + n0 + n) * 256 + c0 + cq * 8) = v;
}

// ---------------- merged f32 -> bf16 weight convert (proj | e | p) ----------------
__global__ void wcvt3(const float* __restrict__ W_proj, const float* __restrict__ W_e,
                      const float* __restrict__ W_p, bf16* __restrict__ o_proj,
                      bf16* __restrict__ o_e, bf16* __restrict__ o_p) {
  const int i = blockIdx.x * 256 + threadIdx.x;
  if (i < 131072) o_proj[i] = (bf16)W_proj[i];
  else if (i < 393216) o_e[i - 131072] = (bf16)W_e[i - 131072];
  else o_p[i - 393216] = (bf16)W_p[i - 393216];
}

// ---------------- W_qkv permuted convert ----------------
__global__ void wqkv_perm(const float* __restrict__ w, bf16* __restrict__ o) {
  const int row = blockIdx.x;  // 0..767 (new index)
  const int t = row >> 8, r = row & 255, h = r >> 5, d = r & 31;
  const int oldrow = h * 96 + t * 32 + d;
  o[row * 256 + threadIdx.x] = (bf16)w[oldrow * 256 + threadIdx.x];
}

// ---------------- MFMA GEMM ----------------
template<int EPI>
__global__ __launch_bounds__(256, 3)
void mfma_gemm(const bf16* __restrict__ A, const bf16* __restrict__ Bact,
               bf16* __restrict__ Yb, float* __restrict__ Yf,
               const int M, const int K,
               const float* __restrict__ p0, const float* __restrict__ p1,
               const bf16* __restrict__ res)
{
  __shared__ __attribute__((aligned(16))) char ldsA[16384];
  __shared__ __attribute__((aligned(16))) char ldsB[16384];
  const int img = blockIdx.z;
  const int n0 = blockIdx.x * 128;
  const int m0 = blockIdx.y * 128;
  const bf16* Bi = Bact + (size_t)img * NPIX * K;
  const int tid = threadIdx.x;
  const int w = tid >> 6, l = tid & 63;
  const int g = l >> 4, ln = l & 15;
  const int wr = w >> 1, wc = w & 1;
  const int lrow = l >> 3;
  const int sofs = (((l & 7) ^ lrow) << 4);

  f32x4 acc[4][4];
#pragma unroll
  for (int i = 0; i < 4; ++i)
#pragma unroll
    for (int j = 0; j < 4; ++j) acc[i][j] = (f32x4){0.f, 0.f, 0.f, 0.f};

  const char* Abase = (const char*)(A + (size_t)m0 * K);
  const char* Bbase = (const char*)(Bi + (size_t)n0 * K);
  const size_t rowb = (size_t)K * 2;
  const int swz = (ln & 7) << 4;

  const int nk = K >> 6;
  for (int kt = 0; kt < nk; ++kt) {
    const int k0b = kt << 7;
#pragma unroll
    for (int i = 0; i < 4; ++i) {
      const int q = (w << 2) + i;
      const int r = q * 8 + lrow;
      gload16(Abase + (size_t)r * rowb + k0b + sofs, ldsA + q * 1024);
    }
#pragma unroll
    for (int i = 0; i < 4; ++i) {
      const int q = (w << 2) + i;
      const int r = q * 8 + lrow;
      gload16(Bbase + (size_t)r * rowb + k0b + sofs, ldsB + q * 1024);
    }
    __syncthreads();
#pragma unroll
    for (int kk = 0; kk < 2; ++kk) {
      bf16x8 av[4], bv[4];
#pragma unroll
      for (int f = 0; f < 4; ++f) {
        const int ra = wr * 64 + f * 16 + ln;
        const int rb = wc * 64 + f * 16 + ln;
        const int kb = kk * 64 + (g << 4);
        av[f] = *(const bf16x8*)(ldsA + ra * 128 + (kb ^ swz));
        bv[f] = *(const bf16x8*)(ldsB + rb * 128 + (kb ^ swz));
      }
#pragma unroll
      for (int fi = 0; fi < 4; ++fi)
#pragma unroll
        for (int fj = 0; fj < 4; ++fj)
          acc[fi][fj] = __builtin_amdgcn_mfma_f32_16x16x32_bf16(
              av[fi], bv[fj], acc[fi][fj], 0, 0, 0);
    }
    __syncthreads();
  }

#pragma unroll
  for (int fi = 0; fi < 4; ++fi) {
    const int m4 = m0 + wr * 64 + fi * 16 + g * 4;
    f32x4 P0 = {0.f, 0.f, 0.f, 0.f}, P1 = {0.f, 0.f, 0.f, 0.f};
    if (EPI == 1 || EPI == 3) { P0 = *(const f32x4*)(p0 + m4); P1 = *(const f32x4*)(p1 + m4); }
    if (EPI == 2) { P0 = *(const f32x4*)(p0 + m4); }
#pragma unroll
    for (int fj = 0; fj < 4; ++fj) {
      const int n = n0 + wc * 64 + fj * 16 + ln;
      if (EPI == 3) {
        const bf16x4 yr = *(const bf16x4*)(res + ((size_t)img * NPIX + n) * 256 + m4);
        float* op = Yf + ((size_t)img * 256 + m4) * NPIX + n;
#pragma unroll
        for (int r = 0; r < 4; ++r)
          op[(size_t)r * NPIX] = P0[r] * BN_SC * acc[fi][fj][r] + P1[r] + (float)yr[r];
      } else {
        bf16x4 sv;
        if (EPI == 0) {
#pragma unroll
          for (int r = 0; r < 4; ++r) sv[r] = (bf16)acc[fi][fj][r];
        } else if (EPI == 1) {
          const bf16x4 xr = *(const bf16x4*)(res + ((size_t)img * NPIX + n) * 256 + m4);
#pragma unroll
          for (int r = 0; r < 4; ++r)
            sv[r] = (bf16)(P0[r] * BN_SC * acc[fi][fj][r] + P1[r] + (float)xr[r]);
        } else {
#pragma unroll
          for (int r = 0; r < 4; ++r)
            sv[r] = (bf16)hswish_f(acc[fi][fj][r] + P0[r]);
        }
        *(bf16x4*)(Yb + ((size_t)img * NPIX + n) * M + m4) = sv;
      }
    }
  }
}

// ---------------- fused dw5x5 + per-group 32x32 pointwise (NHWC), v4.1 ----------------
__global__ __launch_bounds__(512)
void dw5pw_nhwc(const bf16* __restrict__ qkv, const float* __restrict__ W5,
                const float* __restrict__ Wpw, bf16* __restrict__ ag) {
  const int gch = blockIdx.y, img = blockIdx.z;
  const int t_ = gch >> 3, hh_ = gch & 7;
  const int n0 = blockIdx.x * 256;
  const int r0 = n0 >> 6;                        // first of 4 image rows
  __shared__ __attribute__((aligned(16))) unsigned int sInT[16 * 548];  // 35072 B
  __shared__ __attribute__((aligned(16))) unsigned int sS32[256 * 20];  // 20480 B
  __shared__ __attribute__((aligned(16))) bf16 sPw[32 * 32];            // 2048 B
  const int tid = threadIdx.x;
  // halo staging first (longest-latency loads issue earliest)
  for (int i = tid; i < 2176; i += 512) {
    const int s = i & 3, hp = i >> 2;
    const int hr = hp / 68, hc = hp - hr * 68;
    const int gr = r0 + hr - 2, gc = hc - 2;
    uint4 vv = {0u, 0u, 0u, 0u};
    if (gr >= 0 && gr < 64 && gc >= 0 && gc < 64)
      vv = *(const uint4*)(qkv + ((size_t)img * NPIX + gr * 64 + gc) * 768 + gch * 32 + s * 8);
    unsigned int* rp = sInT + (s * 4) * 548 + hp;
    rp[0] = vv.x; rp[548] = vv.y; rp[1096] = vv.z; rp[1644] = vv.w;
  }
  for (int i = tid; i < 1024; i += 512) sPw[i] = (bf16)Wpw[(hh_ * 3 + t_) * 1024 + i];
  // per-thread dw weights for channels {2ci, 2ci+1}
  const int ci = tid & 15;
  f32x2 w2[25];
  {
    const float* wp0 = W5 + (size_t)(hh_ * 96 + t_ * 32 + 2 * ci) * 25;
#pragma unroll
    for (int q = 0; q < 25; ++q) w2[q] = (f32x2){wp0[q], wp0[25 + q]};
  }
  __syncthreads();
  {  // phase 1: depthwise 5x5, packed f32 pairs; pg 0..31, 8 px each
    const int pg = tid >> 4;
    const int p0 = pg * 8;
    const int prow = p0 >> 6, pcol = p0 & 63;
    f32x2 a2[8];
#pragma unroll
    for (int px = 0; px < 8; ++px) a2[px] = (f32x2){0.f, 0.f};
#pragma unroll
    for (int ky = 0; ky < 5; ++ky) {
      const unsigned int* wp = &sInT[ci * 548 + (prow + ky) * 68 + pcol];
      const uint4 qa = *(const uint4*)wp;
      const uint4 qb = *(const uint4*)(wp + 4);
      const uint4 qc = *(const uint4*)(wp + 8);
      const unsigned int win[12] = {qa.x, qa.y, qa.z, qa.w, qb.x, qb.y, qb.z, qb.w,
                                    qc.x, qc.y, qc.z, qc.w};
      f32x2 val[12];
#pragma unroll
      for (int j = 0; j < 12; ++j) val[j] = (f32x2){b2f_lo(win[j]), b2f_hi(win[j])};
#pragma unroll
      for (int px = 0; px < 8; ++px)
#pragma unroll
        for (int kx = 0; kx < 5; ++kx)
          a2[px] = val[px + kx] * w2[ky * 5 + kx] + a2[px];   // v_pk_fma_f32
    }
#pragma unroll
    for (int px = 0; px < 8; ++px) {
      const unsigned int pk = (unsigned int)f2b_u(a2[px][0]) | ((unsigned int)f2b_u(a2[px][1]) << 16);
      sS32[(p0 + px) * 20 + ci] = pk;
    }
  }
  __syncthreads();
  {  // phase 2: pw 32x32 via MFMA; wave w handles p-tiles {2w, 2w+1}
    const int w = tid >> 6, l = tid & 63;
    const int lg = l >> 4, ln = l & 15;
    f32x4 acc[2][2];
#pragma unroll
    for (int i = 0; i < 2; ++i)
#pragma unroll
      for (int j = 0; j < 2; ++j) acc[i][j] = (f32x4){0.f, 0.f, 0.f, 0.f};
    bf16x8 av[2], bv[2];
#pragma unroll
    for (int et = 0; et < 2; ++et)
      av[et] = *(const bf16x8*)((const char*)sPw + (et * 16 + ln) * 64 + lg * 16);
#pragma unroll
    for (int pt = 0; pt < 2; ++pt)
      bv[pt] = *(const bf16x8*)((const char*)sS32 + ((2 * w + pt) * 16 + ln) * 80 + lg * 16);
#pragma unroll
    for (int et = 0; et < 2; ++et)
#pragma unroll
      for (int pt = 0; pt < 2; ++pt)
        acc[et][pt] = __builtin_amdgcn_mfma_f32_16x16x32_bf16(av[et], bv[pt], acc[et][pt], 0, 0, 0);
#pragma unroll
    for (int et = 0; et < 2; ++et)
#pragma unroll
      for (int pt = 0; pt < 2; ++pt) {
        const int e0 = et * 16 + lg * 4;
        const int p = n0 + (2 * w + pt) * 16 + ln;
        bf16x4 sv;
#pragma unroll
        for (int r = 0; r < 4; ++r) sv[r] = (bf16)acc[et][pt][r];
        *(bf16x4*)(ag + ((size_t)img * NPIX + p) * 768 + gch * 32 + e0) = sv;
      }
  }
}

// ---------------- vk partial v2 ----------------
__global__ __launch_bounds__(256)
void vk_part(const bf16* __restrict__ qkv, const bf16* __restrict__ ag,
             float* __restrict__ partial) {
  const int chunk = blockIdx.x, src = blockIdx.y, img = blockIdx.z;
  const bf16* base = (src == 0 ? qkv : ag) + (size_t)img * NPIX * 768 + 256;
  __shared__ __attribute__((aligned(16))) char tile[32 * 1024];
  const int tid = threadIdx.x;
  const int h = tid >> 5;
  const int r5 = tid & 31;
  const int et = r5 & 3;
  const int dq = r5 >> 2;
  const int spx = tid >> 3, sseg = tid & 7;
  f32x2 acc[4][4];
#pragma unroll
  for (int i = 0; i < 4; ++i)
#pragma unroll
    for (int j = 0; j < 4; ++j) acc[i][j] = (f32x2){0.f, 0.f};
  f32x2 dsum[4] = {(f32x2){0.f,0.f},(f32x2){0.f,0.f},(f32x2){0.f,0.f},(f32x2){0.f,0.f}};
  for (int sub = 0; sub < 2; ++sub) {
    __syncthreads();
    {
      const int px0 = chunk * 64 + sub * 32;
      const char* gp = (const char*)(base + (size_t)(px0 + spx) * 768) + sseg * 128;
      char* lp = tile + spx * 1024;
      const int swz = (spx & 7) << 4;
#pragma unroll
      for (int i = 0; i < 8; ++i) {
        uint4 v = *(const uint4*)(gp + i * 16);
        if (sseg < 4) {
          v.x = relu2(v.x); v.y = relu2(v.y); v.z = relu2(v.z); v.w = relu2(v.w);
        }
        *(uint4*)(lp + ((sseg * 128 + i * 16) ^ swz)) = v;
      }
    }
    __syncthreads();
    for (int nn = 0; nn < 32; ++nn) {
      const char* row = tile + nn * 1024;
      const int swzn = (nn & 7) << 4;
      f32x2 kp[4];
#pragma unroll
      for (int j = 0; j < 4; ++j) {
        const unsigned int kk = *(const unsigned int*)(row + ((h * 64 + (et * 4 + j) * 4) ^ swzn));
        kp[j] = (f32x2){b2f_lo(kk), b2f_hi(kk)};
      }
      const unsigned int v0 = *(const unsigned int*)(row + ((512 + h * 64 + dq * 8) ^ swzn));
      const unsigned int v1 = *(const unsigned int*)(row + ((512 + h * 64 + dq * 8 + 4) ^ swzn));
      const float vd[4] = {b2f_lo(v0), b2f_hi(v0), b2f_lo(v1), b2f_hi(v1)};
#pragma unroll
      for (int i = 0; i < 4; ++i)
#pragma unroll
        for (int j = 0; j < 4; ++j)
          acc[i][j] = (f32x2){vd[i], vd[i]} * kp[j] + acc[i][j];
      if (dq == 0) {
#pragma unroll
        for (int j = 0; j < 4; ++j) dsum[j] = dsum[j] + kp[j];
      }
    }
  }
  float* pb = partial + ((size_t)((img * 2 + src) * 64 + chunk)) * 8448;
#pragma unroll
  for (int i = 0; i < 4; ++i) {
    const int d = dq * 4 + i;
#pragma unroll
    for (int j = 0; j < 4; ++j) {
      pb[h * 1056 + d * 32 + et * 8 + j * 2]     = acc[i][j][0];
      pb[h * 1056 + d * 32 + et * 8 + j * 2 + 1] = acc[i][j][1];
    }
  }
  if (dq == 0) {
#pragma unroll
    for (int j = 0; j < 4; ++j) {
      pb[h * 1056 + 1024 + et * 8 + j * 2]     = dsum[j][0];
      pb[h * 1056 + 1024 + et * 8 + j * 2 + 1] = dsum[j][1];
    }
  }
}

// ---------------- vk reduce ----------------
__global__ __launch_bounds__(256)
void vk_reduce(const float* __restrict__ partial, bf16* __restrict__ svkT,
               float* __restrict__ dvec) {
  const int h = blockIdx.x & 15, img = blockIdx.x >> 4;
  const int tid = threadIdx.x;
  const int e = tid & 31, dq = tid >> 5;
  const int src = h >> 3, hh = h & 7;
  const float* pb = partial + (size_t)((img * 2 + src) * 64) * 8448 + hh * 1056;
  float a[4] = {};
  for (int c = 0; c < 64; ++c) {
    const float* pc = pb + (size_t)c * 8448;
#pragma unroll
    for (int j = 0; j < 4; ++j) a[j] += pc[(dq * 4 + j) * 32 + e];
  }
  bf16x4 o;
#pragma unroll
  for (int j = 0; j < 4; ++j) o[j] = (bf16)a[j];
  *(bf16x4*)(svkT + (((size_t)img * 16 + h) * 32 + e) * 32 + dq * 4) = o;
  if (dq == 0) {
    float ds = 0.f;
    for (int c = 0; c < 64; ++c) ds += pb[(size_t)c * 8448 + 1024 + e];
    dvec[((size_t)img * 16 + h) * 32 + e] = ds;
  }
}

// ---------------- attention apply v3: packed-f32 inner math ----------------
__global__ __launch_bounds__(256)
void att_pix(const bf16* __restrict__ qkv, const bf16* __restrict__ ag,
             const bf16* __restrict__ svkT, const float* __restrict__ dvec,
             bf16* __restrict__ att) {
  const int pc = blockIdx.x;      // 16 px each
  const int img = blockIdx.z;
  __shared__ __attribute__((aligned(16))) unsigned int squ[16][264];
  __shared__ __attribute__((aligned(16))) bf16 ssvk[16 * 1024];
  __shared__ __attribute__((aligned(8))) float sdv[512];
  const int tid = threadIdx.x;
  const int px0 = pc * 16;
  const int px = tid >> 4, s = tid & 15;
  {
    const bf16* srcp = (s < 8 ? qkv : ag) + (size_t)(img * NPIX + px0 + px) * 768 + (s & 7) * 32;
#pragma unroll
    for (int i = 0; i < 4; ++i) {
      uint4 v = *(const uint4*)((const char*)srcp + i * 16);
      v.x = relu2(v.x); v.y = relu2(v.y); v.z = relu2(v.z); v.w = relu2(v.w);
      *(uint4*)&squ[px][s * 16 + i * 4] = v;
    }
  }
  {
    const bf16* sb = svkT + (size_t)img * 16384;
    for (int i = tid; i < 2048; i += 256)
      *(bf16x8*)(ssvk + i * 8) = *(const bf16x8*)(sb + i * 8);
    const float* db = dvec + (size_t)img * 512;
    for (int i = tid; i < 512; i += 256) sdv[i] = db[i];
  }
  __syncthreads();
  const int sd = s, d0 = sd * 2;
  const unsigned int* sv32 = (const unsigned int*)ssvk;
  bf16* ob = att + (size_t)(img * NPIX + px0 + px) * 512;
#pragma unroll
  for (int h = 0; h < 16; ++h) {
    const unsigned int* qp = &squ[px][h * 16];
    const unsigned int* kp = sv32 + h * 512 + sd;
    const f32x2* dp = (const f32x2*)&sdv[h * 32];
    f32x2 accp = (f32x2){0.f, 0.f};
    f32x2 denp = (f32x2){0.f, 0.f};
#pragma unroll
    for (int e2 = 0; e2 < 16; ++e2) {
      const unsigned int qq = qp[e2];
      const float q0 = b2f_lo(qq), q1 = b2f_hi(qq);
      const unsigned int w0 = kp[(2 * e2) * 16];
      const unsigned int w1 = kp[(2 * e2 + 1) * 16];
      const f32x2 w0p = (f32x2){b2f_lo(w0), b2f_hi(w0)};
      const f32x2 w1p = (f32x2){b2f_lo(w1), b2f_hi(w1)};
      accp = (f32x2){q0, q0} * w0p + accp;
      accp = (f32x2){q1, q1} * w1p + accp;
      denp = (f32x2){q0, q1} * dp[e2] + denp;
    }
    const float inv = 1.f / (denp[0] + denp[1] + ATT_EPS);
    bf16x2 o; o[0] = (bf16)(accp[0] * inv); o[1] = (bf16)(accp[1] * inv);
    *(bf16x2*)(ob + h * 32 + d0) = o;
  }
}

// ---------------- depthwise 3x3 + bias + hswish (NHWC), v3: 2-col register block ----
// thread = (4 channels, 2 columns); walks 32 rows; 4-col rolling window in regs.
#define DW3_LOADROW4(r, sl)                                                    \
  {                                                                            \
    for (int cs = 0; cs < 4; ++cs) {                                           \
      const int cc = col0 - 1 + cs;                                            \
      if ((unsigned)(r) < 64u && (unsigned)cc < 64u) {                         \
        const uint2 v = *(const uint2*)(ib + (size_t)((r) * 64 + cc) * 1024);  \
        rr[sl][cs][0] = (f32x2){b2f_lo(v.x), b2f_hi(v.x)};                     \
        rr[sl][cs][1] = (f32x2){b2f_lo(v.y), b2f_hi(v.y)};                     \
      } else {                                                                 \
        rr[sl][cs][0] = (f32x2){0.f, 0.f};                                     \
        rr[sl][cs][1] = (f32x2){0.f, 0.f};                                     \
      }                                                                        \
    }                                                                          \
  }

__global__ __launch_bounds__(256)
void dw3_nhwc(const bf16* __restrict__ ein, const float* __restrict__ w3,
              const float* __restrict__ bias, bf16* __restrict__ dout) {
  const int img = blockIdx.z;
  const int r0 = blockIdx.y * 32;
  const int col0 = blockIdx.x * 2;         // output cols col0, col0+1
  const int tid = threadIdx.x;
  const int ch = tid * 4;
  f32x2 wv[9][2];
#pragma unroll
  for (int p = 0; p < 2; ++p)
#pragma unroll
    for (int q = 0; q < 9; ++q)
      wv[q][p] = (f32x2){w3[(ch + 2 * p) * 9 + q], w3[(ch + 2 * p + 1) * 9 + q]};
  f32x2 bv[2];
  bv[0] = (f32x2){bias[ch], bias[ch + 1]};
  bv[1] = (f32x2){bias[ch + 2], bias[ch + 3]};
  const bf16* ib = ein + (size_t)img * NPIX * 1024 + ch;
  bf16* ob = dout + (size_t)img * NPIX * 1024 + ch;
  f32x2 rr[3][4][2];
  DW3_LOADROW4(r0 - 1, 0);
  DW3_LOADROW4(r0, 1);
#pragma unroll
  for (int i = 0; i < 32; ++i) {
    const int slm = i % 3, sl0 = (i + 1) % 3, slp = (i + 2) % 3;
    DW3_LOADROW4(r0 + i + 1, slp);
    f32x2 a0[2] = {bv[0], bv[1]};
    f32x2 a1[2] = {bv[0], bv[1]};
#pragma unroll
    for (int kx = 0; kx < 3; ++kx)
#pragma unroll
      for (int p = 0; p < 2; ++p) {
        a0[p] = rr[slm][kx][p]     * wv[0 * 3 + kx][p] + a0[p];
        a0[p] = rr[sl0][kx][p]     * wv[1 * 3 + kx][p] + a0[p];
        a0[p] = rr[slp][kx][p]     * wv[2 * 3 + kx][p] + a0[p];
        a1[p] = rr[slm][kx + 1][p] * wv[0 * 3 + kx][p] + a1[p];
        a1[p] = rr[sl0][kx + 1][p] * wv[1 * 3 + kx][p] + a1[p];
        a1[p] = rr[slp][kx + 1][p] * wv[2 * 3 + kx][p] + a1[p];
      }
    uint2 o0, o1;
    o0.x = (unsigned)f2b_u(hswish_f(a0[0][0])) | ((unsigned)f2b_u(hswish_f(a0[0][1])) << 16);
    o0.y = (unsigned)f2b_u(hswish_f(a0[1][0])) | ((unsigned)f2b_u(hswish_f(a0[1][1])) << 16);
    o1.x = (unsigned)f2b_u(hswish_f(a1[0][0])) | ((unsigned)f2b_u(hswish_f(a1[0][1])) << 16);
    o1.y = (unsigned)f2b_u(hswish_f(a1[1][0])) | ((unsigned)f2b_u(hswish_f(a1[1][1])) << 16);
    *(uint2*)(ob + (size_t)((r0 + i) * 64 + col0) * 1024)       = o0;
    *(uint2*)(ob + (size_t)((r0 + i) * 64 + col0 + 1) * 1024)   = o1;
  }
}

// ---------------- launch ----------------
extern "C" void kernel_launch(void* const* d_in, const int* in_sizes, int n_in,
                              void* d_out, int out_size, void* d_ws, size_t ws_size,
                              hipStream_t stream) {
  const float* x      = (const float*)d_in[0];
  const float* W_qkv  = (const float*)d_in[1];
  const float* W_dw5  = (const float*)d_in[2];
  const float* W_pw   = (const float*)d_in[3];
  const float* W_proj = (const float*)d_in[4];
  const float* g_proj = (const float*)d_in[5];
  const float* b_proj = (const float*)d_in[6];
  const float* W_e    = (const float*)d_in[7];
  const float* b_e    = (const float*)d_in[8];
  const float* W_dw3  = (const float*)d_in[9];
  const float* b_dw3  = (const float*)d_in[10];
  const float* W_p    = (const float*)d_in[11];
  const float* g_p    = (const float*)d_in[12];
  const float* b_p    = (const float*)d_in[13];
  float* out = (float*)d_out;

  int nb = 8;
  while (nb > 1) {
    size_t need = (size_t)nb * 25331712ull + 1703936ull + 1024;
    if (need <= ws_size) break;
    nb >>= 1;
  }

  char* p = (char*)d_ws;
  float* partial = (float*)p;                 p += (size_t)nb * 4325376;
  float* dvec    = (float*)p;                 p += (size_t)nb * 2048;
  bf16* wq_bf    = (bf16*)p;                  p += 196608ull * 2;
  bf16* wproj_bf = (bf16*)p;                  p += 131072ull * 2;
  bf16* we_bf    = (bf16*)p;                  p += 262144ull * 2;
  bf16* wp_bf    = (bf16*)p;                  p += 262144ull * 2;
  bf16* svkT     = (bf16*)p;                  p += (size_t)nb * 32768;
  bf16* arena    = (bf16*)p;
  bf16* xn   = arena;
  bf16* qkvb = arena + (size_t)nb * 1048576;
  bf16* agb  = qkvb + (size_t)nb * 3145728;
  bf16* attb = agb + (size_t)nb * 3145728;
  bf16* yb   = attb + (size_t)nb * 2097152;
  bf16* eb   = qkvb;
  bf16* db   = qkvb + (size_t)nb * 4194304;

  wqkv_perm<<<768, 256, 0, stream>>>(W_qkv, wq_bf);
  wcvt3<<<2560, 256, 0, stream>>>(W_proj, W_e, W_p, wproj_bf, we_bf, wp_bf);

  for (int b0 = 0; b0 < 8; b0 += nb) {
    const float* x_c = x + (size_t)b0 * 256 * NPIX;
    float* out_c = out + (size_t)b0 * 256 * NPIX;

    x_to_nhwc<<<dim3(64, 8, nb), 256, 0, stream>>>(x_c, xn);
    mfma_gemm<0><<<dim3(32, 6, nb), 256, 0, stream>>>(wq_bf, xn, qkvb, nullptr,
                                                      768, 256, nullptr, nullptr, nullptr);
    dw5pw_nhwc<<<dim3(16, 24, nb), 512, 0, stream>>>(qkvb, W_dw5, W_pw, agb);
    vk_part<<<dim3(64, 2, nb), 256, 0, stream>>>(qkvb, agb, partial);
    vk_reduce<<<nb * 16, 256, 0, stream>>>(partial, svkT, dvec);
    att_pix<<<dim3(256, 1, nb), 256, 0, stream>>>(qkvb, agb, svkT, dvec, attb);
    mfma_gemm<1><<<dim3(32, 2, nb), 256, 0, stream>>>(wproj_bf, attb, yb, nullptr,
                                                      256, 512, g_proj, b_proj, xn);
    mfma_gemm<2><<<dim3(32, 8, nb), 256, 0, stream>>>(we_bf, yb, eb, nullptr,
                                                      1024, 256, b_e, nullptr, nullptr);
    dw3_nhwc<<<dim3(32, 2, nb), 256, 0, stream>>>(eb, W_dw3, b_dw3, db);
    mfma_gemm<3><<<dim3(32, 2, nb), 256, 0, stream>>>(wp_bf, db, nullptr, out_c,
                                                      256, 1024, g_p, b_p, yb);
  }
}

// Round 15
// 361.602 us; speedup vs baseline: 1.0408x; 1.0035x over previous
//
#include <hip/hip_runtime.h>

typedef __bf16 bf16;
typedef __attribute__((ext_vector_type(8))) __bf16 bf16x8;
typedef __attribute__((ext_vector_type(4))) __bf16 bf16x4;
typedef __attribute__((ext_vector_type(2))) __bf16 bf16x2;
typedef __attribute__((ext_vector_type(4))) float f32x4;
typedef __attribute__((ext_vector_type(2))) float f32x2;

static constexpr int NPIX = 4096;                    // 64*64
static constexpr float BN_SC = 0.9999950000374997f;  // 1/sqrt(1+1e-5)
static constexpr float ATT_EPS = 1e-15f;

__device__ __forceinline__ float hswish_f(float v) {
  return v * fminf(fmaxf(v + 3.0f, 0.0f), 6.0f) * (1.0f / 6.0f);
}

__device__ __forceinline__ void gload16(const void* g, void* l) {
  __builtin_amdgcn_global_load_lds(
      (const __attribute__((address_space(1))) unsigned int*)g,
      (__attribute__((address_space(3))) unsigned int*)l, 16, 0, 0);
}

__device__ __forceinline__ float b2f_lo(unsigned int u) {
  union { unsigned int i; float f; } v; v.i = u << 16; return v.f;
}
__device__ __forceinline__ float b2f_hi(unsigned int u) {
  union { unsigned int i; float f; } v; v.i = u & 0xffff0000u; return v.f;
}
__device__ __forceinline__ unsigned short f2b_u(float f) {
  union { float f; unsigned int i; } v; v.f = f;
  unsigned int r = v.i + 0x7FFFu + ((v.i >> 16) & 1u);
  return (unsigned short)(r >> 16);
}
// relu on 2 packed bf16 in a u32
__device__ __forceinline__ unsigned int relu2(unsigned int v) {
  const unsigned int s = v & 0x80008000u;
  const unsigned int m = (s >> 15) * 0xFFFFu;
  return v & ~m;
}

// ---------------- x (f32 NCHW) -> x_nhwc (bf16), v2 coalesced writes ----------------
__global__ __launch_bounds__(256)
void x_to_nhwc(const float* __restrict__ x, bf16* __restrict__ xn) {
  __shared__ float t[32][65];
  __shared__ __attribute__((aligned(16))) bf16 xt[64 * 256];   // 32 KB, rows XOR-swizzled
  const int img = blockIdx.z;
  const int n0 = blockIdx.x * 64;
  const int tid = threadIdx.x;
  for (int c0 = 0; c0 < 256; c0 += 32) {
    const float* xb = x + ((size_t)img * 256 + c0) * NPIX + n0;
    __syncthreads();
    {
      const int col = tid & 63, r0 = tid >> 6;
#pragma unroll
      for (int i = 0; i < 8; ++i) {
        const int r = r0 + i * 4;
        t[r][col] = xb[(size_t)r * NPIX + col];
      }
    }
    __syncthreads();
    const int n = tid & 63, cq = tid >> 6;
    bf16x8 v;
#pragma unroll
    for (int j = 0; j < 8; ++j) v[j] = (bf16)t[cq * 8 + j][n];
    const int byte = n * 512 + (((c0 + cq * 8) * 2) ^ ((n & 7) << 4));
    *(bf16x8*)((char*)xt + byte) = v;
  }
  __syncthreads();
  bf16* dst = xn + ((size_t)img * NPIX + n0) * 256;
  for (int i = tid; i < 2048; i += 256) {
    const int row = i >> 5;
    const int sb = row * 512 + (((i & 31) * 16) ^ ((row & 7) << 4));
    *(uint4*)((char*)dst + i * 16) = *(const uint4*)((const char*)xt + sb);
  }
}

// ---------------- merged f32 -> bf16 weight convert (proj | e | p) ----------------
__global__ void wcvt3(const float* __restrict__ W_proj, const float* __restrict__ W_e,
                      const float* __restrict__ W_p, bf16* __restrict__ o_proj,
                      bf16* __restrict__ o_e, bf16* __restrict__ o_p) {
  const int i = blockIdx.x * 256 + threadIdx.x;
  if (i < 131072) o_proj[i] = (bf16)W_proj[i];
  else if (i < 393216) o_e[i - 131072] = (bf16)W_e[i - 131072];
  else o_p[i - 393216] = (bf16)W_p[i - 393216];
}

// ---------------- W_qkv permuted convert ----------------
__global__ void wqkv_perm(const float* __restrict__ w, bf16* __restrict__ o) {
  const int row = blockIdx.x;  // 0..767 (new index)
  const int t = row >> 8, r = row & 255, h = r >> 5, d = r & 31;
  const int oldrow = h * 96 + t * 32 + d;
  o[row * 256 + threadIdx.x] = (bf16)w[oldrow * 256 + threadIdx.x];
}

// ---------------- MFMA GEMM ----------------
template<int EPI>
__global__ __launch_bounds__(256, 3)
void mfma_gemm(const bf16* __restrict__ A, const bf16* __restrict__ Bact,
               bf16* __restrict__ Yb, float* __restrict__ Yf,
               const int M, const int K,
               const float* __restrict__ p0, const float* __restrict__ p1,
               const bf16* __restrict__ res)
{
  __shared__ __attribute__((aligned(16))) char ldsA[16384];
  __shared__ __attribute__((aligned(16))) char ldsB[16384];
  const int img = blockIdx.z;
  const int n0 = blockIdx.x * 128;
  const int m0 = blockIdx.y * 128;
  const bf16* Bi = Bact + (size_t)img * NPIX * K;
  const int tid = threadIdx.x;
  const int w = tid >> 6, l = tid & 63;
  const int g = l >> 4, ln = l & 15;
  const int wr = w >> 1, wc = w & 1;
  const int lrow = l >> 3;
  const int sofs = (((l & 7) ^ lrow) << 4);

  f32x4 acc[4][4];
#pragma unroll
  for (int i = 0; i < 4; ++i)
#pragma unroll
    for (int j = 0; j < 4; ++j) acc[i][j] = (f32x4){0.f, 0.f, 0.f, 0.f};

  const char* Abase = (const char*)(A + (size_t)m0 * K);
  const char* Bbase = (const char*)(Bi + (size_t)n0 * K);
  const size_t rowb = (size_t)K * 2;
  const int swz = (ln & 7) << 4;

  const int nk = K >> 6;
  for (int kt = 0; kt < nk; ++kt) {
    const int k0b = kt << 7;
#pragma unroll
    for (int i = 0; i < 4; ++i) {
      const int q = (w << 2) + i;
      const int r = q * 8 + lrow;
      gload16(Abase + (size_t)r * rowb + k0b + sofs, ldsA + q * 1024);
    }
#pragma unroll
    for (int i = 0; i < 4; ++i) {
      const int q = (w << 2) + i;
      const int r = q * 8 + lrow;
      gload16(Bbase + (size_t)r * rowb + k0b + sofs, ldsB + q * 1024);
    }
    __syncthreads();
#pragma unroll
    for (int kk = 0; kk < 2; ++kk) {
      bf16x8 av[4], bv[4];
#pragma unroll
      for (int f = 0; f < 4; ++f) {
        const int ra = wr * 64 + f * 16 + ln;
        const int rb = wc * 64 + f * 16 + ln;
        const int kb = kk * 64 + (g << 4);
        av[f] = *(const bf16x8*)(ldsA + ra * 128 + (kb ^ swz));
        bv[f] = *(const bf16x8*)(ldsB + rb * 128 + (kb ^ swz));
      }
#pragma unroll
      for (int fi = 0; fi < 4; ++fi)
#pragma unroll
        for (int fj = 0; fj < 4; ++fj)
          acc[fi][fj] = __builtin_amdgcn_mfma_f32_16x16x32_bf16(
              av[fi], bv[fj], acc[fi][fj], 0, 0, 0);
    }
    __syncthreads();
  }

#pragma unroll
  for (int fi = 0; fi < 4; ++fi) {
    const int m4 = m0 + wr * 64 + fi * 16 + g * 4;
    f32x4 P0 = {0.f, 0.f, 0.f, 0.f}, P1 = {0.f, 0.f, 0.f, 0.f};
    if (EPI == 1 || EPI == 3) { P0 = *(const f32x4*)(p0 + m4); P1 = *(const f32x4*)(p1 + m4); }
    if (EPI == 2) { P0 = *(const f32x4*)(p0 + m4); }
#pragma unroll
    for (int fj = 0; fj < 4; ++fj) {
      const int n = n0 + wc * 64 + fj * 16 + ln;
      if (EPI == 3) {
        const bf16x4 yr = *(const bf16x4*)(res + ((size_t)img * NPIX + n) * 256 + m4);
        float* op = Yf + ((size_t)img * 256 + m4) * NPIX + n;
#pragma unroll
        for (int r = 0; r < 4; ++r)
          op[(size_t)r * NPIX] = P0[r] * BN_SC * acc[fi][fj][r] + P1[r] + (float)yr[r];
      } else {
        bf16x4 sv;
        if (EPI == 0) {
#pragma unroll
          for (int r = 0; r < 4; ++r) sv[r] = (bf16)acc[fi][fj][r];
        } else if (EPI == 1) {
          const bf16x4 xr = *(const bf16x4*)(res + ((size_t)img * NPIX + n) * 256 + m4);
#pragma unroll
          for (int r = 0; r < 4; ++r)
            sv[r] = (bf16)(P0[r] * BN_SC * acc[fi][fj][r] + P1[r] + (float)xr[r]);
        } else {
#pragma unroll
          for (int r = 0; r < 4; ++r)
            sv[r] = (bf16)hswish_f(acc[fi][fj][r] + P0[r]);
        }
        *(bf16x4*)(Yb + ((size_t)img * NPIX + n) * M + m4) = sv;
      }
    }
  }
}

// ---------------- fused dw5x5 + per-group 32x32 pointwise (NHWC), v4.1 ----------------
__global__ __launch_bounds__(512)
void dw5pw_nhwc(const bf16* __restrict__ qkv, const float* __restrict__ W5,
                const float* __restrict__ Wpw, bf16* __restrict__ ag) {
  const int gch = blockIdx.y, img = blockIdx.z;
  const int t_ = gch >> 3, hh_ = gch & 7;
  const int n0 = blockIdx.x * 256;
  const int r0 = n0 >> 6;                        // first of 4 image rows
  __shared__ __attribute__((aligned(16))) unsigned int sInT[16 * 548];  // 35072 B
  __shared__ __attribute__((aligned(16))) unsigned int sS32[256 * 20];  // 20480 B
  __shared__ __attribute__((aligned(16))) bf16 sPw[32 * 32];            // 2048 B
  const int tid = threadIdx.x;
  // halo staging first (longest-latency loads issue earliest)
  for (int i = tid; i < 2176; i += 512) {
    const int s = i & 3, hp = i >> 2;
    const int hr = hp / 68, hc = hp - hr * 68;
    const int gr = r0 + hr - 2, gc = hc - 2;
    uint4 vv = {0u, 0u, 0u, 0u};
    if (gr >= 0 && gr < 64 && gc >= 0 && gc < 64)
      vv = *(const uint4*)(qkv + ((size_t)img * NPIX + gr * 64 + gc) * 768 + gch * 32 + s * 8);
    unsigned int* rp = sInT + (s * 4) * 548 + hp;
    rp[0] = vv.x; rp[548] = vv.y; rp[1096] = vv.z; rp[1644] = vv.w;
  }
  for (int i = tid; i < 1024; i += 512) sPw[i] = (bf16)Wpw[(hh_ * 3 + t_) * 1024 + i];
  // per-thread dw weights for channels {2ci, 2ci+1}
  const int ci = tid & 15;
  f32x2 w2[25];
  {
    const float* wp0 = W5 + (size_t)(hh_ * 96 + t_ * 32 + 2 * ci) * 25;
#pragma unroll
    for (int q = 0; q < 25; ++q) w2[q] = (f32x2){wp0[q], wp0[25 + q]};
  }
  __syncthreads();
  {  // phase 1: depthwise 5x5, packed f32 pairs; pg 0..31, 8 px each
    const int pg = tid >> 4;
    const int p0 = pg * 8;
    const int prow = p0 >> 6, pcol = p0 & 63;
    f32x2 a2[8];
#pragma unroll
    for (int px = 0; px < 8; ++px) a2[px] = (f32x2){0.f, 0.f};
#pragma unroll
    for (int ky = 0; ky < 5; ++ky) {
      const unsigned int* wp = &sInT[ci * 548 + (prow + ky) * 68 + pcol];
      const uint4 qa = *(const uint4*)wp;
      const uint4 qb = *(const uint4*)(wp + 4);
      const uint4 qc = *(const uint4*)(wp + 8);
      const unsigned int win[12] = {qa.x, qa.y, qa.z, qa.w, qb.x, qb.y, qb.z, qb.w,
                                    qc.x, qc.y, qc.z, qc.w};
      f32x2 val[12];
#pragma unroll
      for (int j = 0; j < 12; ++j) val[j] = (f32x2){b2f_lo(win[j]), b2f_hi(win[j])};
#pragma unroll
      for (int px = 0; px < 8; ++px)
#pragma unroll
        for (int kx = 0; kx < 5; ++kx)
          a2[px] = val[px + kx] * w2[ky * 5 + kx] + a2[px];   // v_pk_fma_f32
    }
#pragma unroll
    for (int px = 0; px < 8; ++px) {
      const unsigned int pk = (unsigned int)f2b_u(a2[px][0]) | ((unsigned int)f2b_u(a2[px][1]) << 16);
      sS32[(p0 + px) * 20 + ci] = pk;
    }
  }
  __syncthreads();
  {  // phase 2: pw 32x32 via MFMA; wave w handles p-tiles {2w, 2w+1}
    const int w = tid >> 6, l = tid & 63;
    const int lg = l >> 4, ln = l & 15;
    f32x4 acc[2][2];
#pragma unroll
    for (int i = 0; i < 2; ++i)
#pragma unroll
      for (int j = 0; j < 2; ++j) acc[i][j] = (f32x4){0.f, 0.f, 0.f, 0.f};
    bf16x8 av[2], bv[2];
#pragma unroll
    for (int et = 0; et < 2; ++et)
      av[et] = *(const bf16x8*)((const char*)sPw + (et * 16 + ln) * 64 + lg * 16);
#pragma unroll
    for (int pt = 0; pt < 2; ++pt)
      bv[pt] = *(const bf16x8*)((const char*)sS32 + ((2 * w + pt) * 16 + ln) * 80 + lg * 16);
#pragma unroll
    for (int et = 0; et < 2; ++et)
#pragma unroll
      for (int pt = 0; pt < 2; ++pt)
        acc[et][pt] = __builtin_amdgcn_mfma_f32_16x16x32_bf16(av[et], bv[pt], acc[et][pt], 0, 0, 0);
#pragma unroll
    for (int et = 0; et < 2; ++et)
#pragma unroll
      for (int pt = 0; pt < 2; ++pt) {
        const int e0 = et * 16 + lg * 4;
        const int p = n0 + (2 * w + pt) * 16 + ln;
        bf16x4 sv;
#pragma unroll
        for (int r = 0; r < 4; ++r) sv[r] = (bf16)acc[et][pt][r];
        *(bf16x4*)(ag + ((size_t)img * NPIX + p) * 768 + gch * 32 + e0) = sv;
      }
  }
}

// ---------------- vk partial v2 ----------------
__global__ __launch_bounds__(256)
void vk_part(const bf16* __restrict__ qkv, const bf16* __restrict__ ag,
             float* __restrict__ partial) {
  const int chunk = blockIdx.x, src = blockIdx.y, img = blockIdx.z;
  const bf16* base = (src == 0 ? qkv : ag) + (size_t)img * NPIX * 768 + 256;
  __shared__ __attribute__((aligned(16))) char tile[32 * 1024];
  const int tid = threadIdx.x;
  const int h = tid >> 5;
  const int r5 = tid & 31;
  const int et = r5 & 3;
  const int dq = r5 >> 2;
  const int spx = tid >> 3, sseg = tid & 7;
  f32x2 acc[4][4];
#pragma unroll
  for (int i = 0; i < 4; ++i)
#pragma unroll
    for (int j = 0; j < 4; ++j) acc[i][j] = (f32x2){0.f, 0.f};
  f32x2 dsum[4] = {(f32x2){0.f,0.f},(f32x2){0.f,0.f},(f32x2){0.f,0.f},(f32x2){0.f,0.f}};
  for (int sub = 0; sub < 2; ++sub) {
    __syncthreads();
    {
      const int px0 = chunk * 64 + sub * 32;
      const char* gp = (const char*)(base + (size_t)(px0 + spx) * 768) + sseg * 128;
      char* lp = tile + spx * 1024;
      const int swz = (spx & 7) << 4;
#pragma unroll
      for (int i = 0; i < 8; ++i) {
        uint4 v = *(const uint4*)(gp + i * 16);
        if (sseg < 4) {
          v.x = relu2(v.x); v.y = relu2(v.y); v.z = relu2(v.z); v.w = relu2(v.w);
        }
        *(uint4*)(lp + ((sseg * 128 + i * 16) ^ swz)) = v;
      }
    }
    __syncthreads();
    for (int nn = 0; nn < 32; ++nn) {
      const char* row = tile + nn * 1024;
      const int swzn = (nn & 7) << 4;
      f32x2 kp[4];
#pragma unroll
      for (int j = 0; j < 4; ++j) {
        const unsigned int kk = *(const unsigned int*)(row + ((h * 64 + (et * 4 + j) * 4) ^ swzn));
        kp[j] = (f32x2){b2f_lo(kk), b2f_hi(kk)};
      }
      const unsigned int v0 = *(const unsigned int*)(row + ((512 + h * 64 + dq * 8) ^ swzn));
      const unsigned int v1 = *(const unsigned int*)(row + ((512 + h * 64 + dq * 8 + 4) ^ swzn));
      const float vd[4] = {b2f_lo(v0), b2f_hi(v0), b2f_lo(v1), b2f_hi(v1)};
#pragma unroll
      for (int i = 0; i < 4; ++i)
#pragma unroll
        for (int j = 0; j < 4; ++j)
          acc[i][j] = (f32x2){vd[i], vd[i]} * kp[j] + acc[i][j];
      if (dq == 0) {
#pragma unroll
        for (int j = 0; j < 4; ++j) dsum[j] = dsum[j] + kp[j];
      }
    }
  }
  float* pb = partial + ((size_t)((img * 2 + src) * 64 + chunk)) * 8448;
#pragma unroll
  for (int i = 0; i < 4; ++i) {
    const int d = dq * 4 + i;
#pragma unroll
    for (int j = 0; j < 4; ++j) {
      pb[h * 1056 + d * 32 + et * 8 + j * 2]     = acc[i][j][0];
      pb[h * 1056 + d * 32 + et * 8 + j * 2 + 1] = acc[i][j][1];
    }
  }
  if (dq == 0) {
#pragma unroll
    for (int j = 0; j < 4; ++j) {
      pb[h * 1056 + 1024 + et * 8 + j * 2]     = dsum[j][0];
      pb[h * 1056 + 1024 + et * 8 + j * 2 + 1] = dsum[j][1];
    }
  }
}

// ---------------- vk reduce ----------------
__global__ __launch_bounds__(256)
void vk_reduce(const float* __restrict__ partial, bf16* __restrict__ svkT,
               float* __restrict__ dvec) {
  const int h = blockIdx.x & 15, img = blockIdx.x >> 4;
  const int tid = threadIdx.x;
  const int e = tid & 31, dq = tid >> 5;
  const int src = h >> 3, hh = h & 7;
  const float* pb = partial + (size_t)((img * 2 + src) * 64) * 8448 + hh * 1056;
  float a[4] = {};
  for (int c = 0; c < 64; ++c) {
    const float* pc = pb + (size_t)c * 8448;
#pragma unroll
    for (int j = 0; j < 4; ++j) a[j] += pc[(dq * 4 + j) * 32 + e];
  }
  bf16x4 o;
#pragma unroll
  for (int j = 0; j < 4; ++j) o[j] = (bf16)a[j];
  *(bf16x4*)(svkT + (((size_t)img * 16 + h) * 32 + e) * 32 + dq * 4) = o;
  if (dq == 0) {
    float ds = 0.f;
    for (int c = 0; c < 64; ++c) ds += pb[(size_t)c * 8448 + 1024 + e];
    dvec[((size_t)img * 16 + h) * 32 + e] = ds;
  }
}

// ---------------- attention apply v3: packed-f32 inner math ----------------
__global__ __launch_bounds__(256)
void att_pix(const bf16* __restrict__ qkv, const bf16* __restrict__ ag,
             const bf16* __restrict__ svkT, const float* __restrict__ dvec,
             bf16* __restrict__ att) {
  const int pc = blockIdx.x;      // 16 px each
  const int img = blockIdx.z;
  __shared__ __attribute__((aligned(16))) unsigned int squ[16][264];
  __shared__ __attribute__((aligned(16))) bf16 ssvk[16 * 1024];
  __shared__ __attribute__((aligned(8))) float sdv[512];
  const int tid = threadIdx.x;
  const int px0 = pc * 16;
  const int px = tid >> 4, s = tid & 15;
  {
    const bf16* srcp = (s < 8 ? qkv : ag) + (size_t)(img * NPIX + px0 + px) * 768 + (s & 7) * 32;
#pragma unroll
    for (int i = 0; i < 4; ++i) {
      uint4 v = *(const uint4*)((const char*)srcp + i * 16);
      v.x = relu2(v.x); v.y = relu2(v.y); v.z = relu2(v.z); v.w = relu2(v.w);
      *(uint4*)&squ[px][s * 16 + i * 4] = v;
    }
  }
  {
    const bf16* sb = svkT + (size_t)img * 16384;
    for (int i = tid; i < 2048; i += 256)
      *(bf16x8*)(ssvk + i * 8) = *(const bf16x8*)(sb + i * 8);
    const float* db = dvec + (size_t)img * 512;
    for (int i = tid; i < 512; i += 256) sdv[i] = db[i];
  }
  __syncthreads();
  const int sd = s, d0 = sd * 2;
  const unsigned int* sv32 = (const unsigned int*)ssvk;
  bf16* ob = att + (size_t)(img * NPIX + px0 + px) * 512;
#pragma unroll
  for (int h = 0; h < 16; ++h) {
    const unsigned int* qp = &squ[px][h * 16];
    const unsigned int* kp = sv32 + h * 512 + sd;
    const f32x2* dp = (const f32x2*)&sdv[h * 32];
    f32x2 accp = (f32x2){0.f, 0.f};
    f32x2 denp = (f32x2){0.f, 0.f};
#pragma unroll
    for (int e2 = 0; e2 < 16; ++e2) {
      const unsigned int qq = qp[e2];
      const float q0 = b2f_lo(qq), q1 = b2f_hi(qq);
      const unsigned int w0 = kp[(2 * e2) * 16];
      const unsigned int w1 = kp[(2 * e2 + 1) * 16];
      const f32x2 w0p = (f32x2){b2f_lo(w0), b2f_hi(w0)};
      const f32x2 w1p = (f32x2){b2f_lo(w1), b2f_hi(w1)};
      accp = (f32x2){q0, q0} * w0p + accp;
      accp = (f32x2){q1, q1} * w1p + accp;
      denp = (f32x2){q0, q1} * dp[e2] + denp;
    }
    const float inv = 1.f / (denp[0] + denp[1] + ATT_EPS);
    bf16x2 o; o[0] = (bf16)(accp[0] * inv); o[1] = (bf16)(accp[1] * inv);
    *(bf16x2*)(ob + h * 32 + d0) = o;
  }
}

// ---------------- depthwise 3x3 + bias + hswish (NHWC), v3: 2-col register block ----
#define DW3_LOADROW4(r, sl)                                                    \
  {                                                                            \
    for (int cs = 0; cs < 4; ++cs) {                                           \
      const int cc = col0 - 1 + cs;                                            \
      if ((unsigned)(r) < 64u && (unsigned)cc < 64u) {                         \
        const uint2 v = *(const uint2*)(ib + (size_t)((r) * 64 + cc) * 1024);  \
        rr[sl][cs][0] = (f32x2){b2f_lo(v.x), b2f_hi(v.x)};                     \
        rr[sl][cs][1] = (f32x2){b2f_lo(v.y), b2f_hi(v.y)};                     \
      } else {                                                                 \
        rr[sl][cs][0] = (f32x2){0.f, 0.f};                                     \
        rr[sl][cs][1] = (f32x2){0.f, 0.f};                                     \
      }                                                                        \
    }                                                                          \
  }

__global__ __launch_bounds__(256)
void dw3_nhwc(const bf16* __restrict__ ein, const float* __restrict__ w3,
              const float* __restrict__ bias, bf16* __restrict__ dout) {
  const int img = blockIdx.z;
  const int r0 = blockIdx.y * 32;
  const int col0 = blockIdx.x * 2;         // output cols col0, col0+1
  const int tid = threadIdx.x;
  const int ch = tid * 4;
  f32x2 wv[9][2];
#pragma unroll
  for (int p = 0; p < 2; ++p)
#pragma unroll
    for (int q = 0; q < 9; ++q)
      wv[q][p] = (f32x2){w3[(ch + 2 * p) * 9 + q], w3[(ch + 2 * p + 1) * 9 + q]};
  f32x2 bv[2];
  bv[0] = (f32x2){bias[ch], bias[ch + 1]};
  bv[1] = (f32x2){bias[ch + 2], bias[ch + 3]};
  const bf16* ib = ein + (size_t)img * NPIX * 1024 + ch;
  bf16* ob = dout + (size_t)img * NPIX * 1024 + ch;
  f32x2 rr[3][4][2];
  DW3_LOADROW4(r0 - 1, 0);
  DW3_LOADROW4(r0, 1);
#pragma unroll
  for (int i = 0; i < 32; ++i) {
    const int slm = i % 3, sl0 = (i + 1) % 3, slp = (i + 2) % 3;
    DW3_LOADROW4(r0 + i + 1, slp);
    f32x2 a0[2] = {bv[0], bv[1]};
    f32x2 a1[2] = {bv[0], bv[1]};
#pragma unroll
    for (int kx = 0; kx < 3; ++kx)
#pragma unroll
      for (int p = 0; p < 2; ++p) {
        a0[p] = rr[slm][kx][p]     * wv[0 * 3 + kx][p] + a0[p];
        a0[p] = rr[sl0][kx][p]     * wv[1 * 3 + kx][p] + a0[p];
        a0[p] = rr[slp][kx][p]     * wv[2 * 3 + kx][p] + a0[p];
        a1[p] = rr[slm][kx + 1][p] * wv[0 * 3 + kx][p] + a1[p];
        a1[p] = rr[sl0][kx + 1][p] * wv[1 * 3 + kx][p] + a1[p];
        a1[p] = rr[slp][kx + 1][p] * wv[2 * 3 + kx][p] + a1[p];
      }
    uint2 o0, o1;
    o0.x = (unsigned)f2b_u(hswish_f(a0[0][0])) | ((unsigned)f2b_u(hswish_f(a0[0][1])) << 16);
    o0.y = (unsigned)f2b_u(hswish_f(a0[1][0])) | ((unsigned)f2b_u(hswish_f(a0[1][1])) << 16);
    o1.x = (unsigned)f2b_u(hswish_f(a1[0][0])) | ((unsigned)f2b_u(hswish_f(a1[0][1])) << 16);
    o1.y = (unsigned)f2b_u(hswish_f(a1[1][0])) | ((unsigned)f2b_u(hswish_f(a1[1][1])) << 16);
    *(uint2*)(ob + (size_t)((r0 + i) * 64 + col0) * 1024)       = o0;
    *(uint2*)(ob + (size_t)((r0 + i) * 64 + col0 + 1) * 1024)   = o1;
  }
}

// ---------------- launch ----------------
extern "C" void kernel_launch(void* const* d_in, const int* in_sizes, int n_in,
                              void* d_out, int out_size, void* d_ws, size_t ws_size,
                              hipStream_t stream) {
  const float* x      = (const float*)d_in[0];
  const float* W_qkv  = (const float*)d_in[1];
  const float* W_dw5  = (const float*)d_in[2];
  const float* W_pw   = (const float*)d_in[3];
  const float* W_proj = (const float*)d_in[4];
  const float* g_proj = (const float*)d_in[5];
  const float* b_proj = (const float*)d_in[6];
  const float* W_e    = (const float*)d_in[7];
  const float* b_e    = (const float*)d_in[8];
  const float* W_dw3  = (const float*)d_in[9];
  const float* b_dw3  = (const float*)d_in[10];
  const float* W_p    = (const float*)d_in[11];
  const float* g_p    = (const float*)d_in[12];
  const float* b_p    = (const float*)d_in[13];
  float* out = (float*)d_out;

  int nb = 8;
  while (nb > 1) {
    size_t need = (size_t)nb * 25331712ull + 1703936ull + 1024;
    if (need <= ws_size) break;
    nb >>= 1;
  }

  char* p = (char*)d_ws;
  float* partial = (float*)p;                 p += (size_t)nb * 4325376;
  float* dvec    = (float*)p;                 p += (size_t)nb * 2048;
  bf16* wq_bf    = (bf16*)p;                  p += 196608ull * 2;
  bf16* wproj_bf = (bf16*)p;                  p += 131072ull * 2;
  bf16* we_bf    = (bf16*)p;                  p += 262144ull * 2;
  bf16* wp_bf    = (bf16*)p;                  p += 262144ull * 2;
  bf16* svkT     = (bf16*)p;                  p += (size_t)nb * 32768;
  bf16* arena    = (bf16*)p;
  bf16* xn   = arena;
  bf16* qkvb = arena + (size_t)nb * 1048576;
  bf16* agb  = qkvb + (size_t)nb * 3145728;
  bf16* attb = agb + (size_t)nb * 3145728;
  bf16* yb   = attb + (size_t)nb * 2097152;
  bf16* eb   = qkvb;
  bf16* db   = qkvb + (size_t)nb * 4194304;

  wqkv_perm<<<768, 256, 0, stream>>>(W_qkv, wq_bf);
  wcvt3<<<2560, 256, 0, stream>>>(W_proj, W_e, W_p, wproj_bf, we_bf, wp_bf);

  for (int b0 = 0; b0 < 8; b0 += nb) {
    const float* x_c = x + (size_t)b0 * 256 * NPIX;
    float* out_c = out + (size_t)b0 * 256 * NPIX;

    x_to_nhwc<<<dim3(64, 1, nb), 256, 0, stream>>>(x_c, xn);
    mfma_gemm<0><<<dim3(32, 6, nb), 256, 0, stream>>>(wq_bf, xn, qkvb, nullptr,
                                                      768, 256, nullptr, nullptr, nullptr);
    dw5pw_nhwc<<<dim3(16, 24, nb), 512, 0, stream>>>(qkvb, W_dw5, W_pw, agb);
    vk_part<<<dim3(64, 2, nb), 256, 0, stream>>>(qkvb, agb, partial);
    vk_reduce<<<nb * 16, 256, 0, stream>>>(partial, svkT, dvec);
    att_pix<<<dim3(256, 1, nb), 256, 0, stream>>>(qkvb, agb, svkT, dvec, attb);
    mfma_gemm<1><<<dim3(32, 2, nb), 256, 0, stream>>>(wproj_bf, attb, yb, nullptr,
                                                      256, 512, g_proj, b_proj, xn);
    mfma_gemm<2><<<dim3(32, 8, nb), 256, 0, stream>>>(we_bf, yb, eb, nullptr,
                                                      1024, 256, b_e, nullptr, nullptr);
    dw3_nhwc<<<dim3(32, 2, nb), 256, 0, stream>>>(eb, W_dw3, b_dw3, db);
    mfma_gemm<3><<<dim3(32, 2, nb), 256, 0, stream>>>(wp_bf, db, nullptr, out_c,
                                                      256, 1024, g_p, b_p, yb);
  }
}